// Round 7
// baseline (678.892 us; speedup 1.0000x reference)
//
#include <hip/hip_runtime.h>
#include <hip/hip_bf16.h>

#define Bv 2
#define Sv 1024
#define Dv 512
#define Hv 8
#define Nv 512
#define Kv 16
#define NBv 8
#define DFv 2048
#define NTOK (Bv*Sv)   // 2048

typedef __attribute__((ext_vector_type(8))) short short8;
typedef __attribute__((ext_vector_type(4))) float float4v;
typedef __attribute__((ext_vector_type(4))) double dbl4;

// ---------------- LayerNorm f64 (f32 in / f64 out) ----------------
__launch_bounds__(256)
__global__ void ln64_k(const float* __restrict__ x, const float* __restrict__ g,
                       const float* __restrict__ b, double* __restrict__ out)
{
    const int t = blockIdx.x;
    const size_t base = (size_t)t * Dv;
    const int tid = threadIdx.x;
    double v0 = (double)x[base + tid];
    double v1 = (double)x[base + tid + 256];
    double s = v0 + v1, ss = v0 * v0 + v1 * v1;
    #pragma unroll
    for (int off = 32; off; off >>= 1) { s += __shfl_xor(s, off); ss += __shfl_xor(ss, off); }
    __shared__ double red[4][2];
    const int wv = tid >> 6, ln = tid & 63;
    if (ln == 0) { red[wv][0] = s; red[wv][1] = ss; }
    __syncthreads();
    s  = red[0][0] + red[1][0] + red[2][0] + red[3][0];
    ss = red[0][1] + red[1][1] + red[2][1] + red[3][1];
    double mu  = s * (1.0 / Dv);
    double var = ss * (1.0 / Dv) - mu * mu;
    double rstd = 1.0 / sqrt(var + 1e-5);
    out[base + tid]       = (v0 - mu) * rstd * (double)g[tid]       + (double)b[tid];
    out[base + tid + 256] = (v1 - mu) * rstd * (double)g[tid + 256] + (double)b[tid + 256];
}

// ---------------- fused QKV f64 GEMM, self-calibrating MFMA with scalar fallback ----------------
__launch_bounds__(256)
__global__ void qkvMC_k(const double* __restrict__ A,
                        const float* __restrict__ Wq, const float* __restrict__ Wk,
                        const float* __restrict__ Wv, const float* __restrict__ bq,
                        const float* __restrict__ bk, const float* __restrict__ bvv,
                        double* __restrict__ qo, double* __restrict__ ko,
                        double* __restrict__ vo)
{
    __shared__ double As[32][18];
    __shared__ double Bs[3][16][66];
    const int tid = threadIdx.x;
    const int n0 = blockIdx.x * 64, m0 = blockIdx.y * 32;
    const int w = tid >> 6, l = tid & 63;
    const int mt = (w >> 1) * 16, wc = (w & 1) * 32;
    const int ar = tid >> 3, ak = (tid & 7) * 2;
    const int bkk = tid >> 4, bn = (tid & 15) * 4;

    // ---- runtime layout probe (exact small-int arithmetic) ----
    int rA = 0, kA = 0, kB = 0, cB = 0, dsel = -1;
    #pragma unroll 1
    for (int ab = 0; ab < 4; ab++) {
        if (dsel >= 0) break;
        const int a_ = ab & 1, b_ = ab >> 1;
        const int rA_ = a_ ? (l >> 2) : (l & 15);
        const int kA_ = a_ ? (l & 3)  : (l >> 4);
        const int kB_ = b_ ? (l & 3)  : (l >> 4);
        const int cB_ = b_ ? (l >> 2) : (l & 15);
        const double av  = (double)(((rA_ * 37 + kA_ * 11) % 19) + 1);
        const double bvp = (double)(((kB_ * 23 + cB_ * 7) % 17) + 1);
        dbl4 dd = __builtin_amdgcn_mfma_f64_16x16x4f64(av, bvp, (dbl4){0.0, 0.0, 0.0, 0.0}, 0, 0, 0);
        #pragma unroll 1
        for (int d = 0; d < 4; d++) {
            if (dsel >= 0) break;
            int okv = 1;
            #pragma unroll
            for (int r = 0; r < 4; r++) {
                const int i_ = (d == 0) ? 4 * (l >> 4) + r
                             : (d == 1) ? (l & 15)
                             : (d == 2) ? (l >> 4) + 4 * r
                             :            (l & 15);
                const int j_ = (d == 0) ? (l & 15)
                             : (d == 1) ? 4 * (l >> 4) + r
                             : (d == 2) ? (l & 15)
                             :            (l >> 4) + 4 * r;
                double e = 0.0;
                #pragma unroll
                for (int kk2 = 0; kk2 < 4; kk2++)
                    e += (double)(((i_ * 37 + kk2 * 11) % 19) + 1)
                       * (double)(((kk2 * 23 + j_ * 7) % 17) + 1);
                okv &= (dd[r] == e) ? 1 : 0;
            }
            if (__all(okv)) { dsel = d; rA = rA_; kA = kA_; kB = kB_; cB = cB_; }
        }
    }

    auto stage = [&](int k0) {
        double2 avv = *(const double2*)(A + (size_t)(m0 + ar) * Dv + k0 + ak);
        *(double2*)&As[ar][ak] = avv;
        {
            float4 b4 = *(const float4*)(Wq + (size_t)(k0 + bkk) * Dv + n0 + bn);
            Bs[0][bkk][bn] = (double)b4.x; Bs[0][bkk][bn + 1] = (double)b4.y;
            Bs[0][bkk][bn + 2] = (double)b4.z; Bs[0][bkk][bn + 3] = (double)b4.w;
        }
        {
            float4 b4 = *(const float4*)(Wk + (size_t)(k0 + bkk) * Dv + n0 + bn);
            Bs[1][bkk][bn] = (double)b4.x; Bs[1][bkk][bn + 1] = (double)b4.y;
            Bs[1][bkk][bn + 2] = (double)b4.z; Bs[1][bkk][bn + 3] = (double)b4.w;
        }
        {
            float4 b4 = *(const float4*)(Wv + (size_t)(k0 + bkk) * Dv + n0 + bn);
            Bs[2][bkk][bn] = (double)b4.x; Bs[2][bkk][bn + 1] = (double)b4.y;
            Bs[2][bkk][bn + 2] = (double)b4.z; Bs[2][bkk][bn + 3] = (double)b4.w;
        }
    };

    if (dsel >= 0) {
        dbl4 acc[3][2];
        #pragma unroll
        for (int z = 0; z < 3; z++)
            #pragma unroll
            for (int nt = 0; nt < 2; nt++)
                acc[z][nt] = (dbl4){0.0, 0.0, 0.0, 0.0};
        for (int k0 = 0; k0 < Dv; k0 += 16) {
            __syncthreads();
            stage(k0);
            __syncthreads();
            #pragma unroll
            for (int s = 0; s < 4; s++) {
                const double aA = As[mt + rA][4 * s + kA];
                #pragma unroll
                for (int z = 0; z < 3; z++) {
                    const double b0 = Bs[z][4 * s + kB][wc + cB];
                    const double b1 = Bs[z][4 * s + kB][wc + 16 + cB];
                    acc[z][0] = __builtin_amdgcn_mfma_f64_16x16x4f64(aA, b0, acc[z][0], 0, 0, 0);
                    acc[z][1] = __builtin_amdgcn_mfma_f64_16x16x4f64(aA, b1, acc[z][1], 0, 0, 0);
                }
            }
        }
        #pragma unroll
        for (int r = 0; r < 4; r++) {
            const int i_ = (dsel == 0) ? 4 * (l >> 4) + r
                         : (dsel == 1) ? (l & 15)
                         : (dsel == 2) ? (l >> 4) + 4 * r
                         :               (l & 15);
            const int j_ = (dsel == 0) ? (l & 15)
                         : (dsel == 1) ? 4 * (l >> 4) + r
                         : (dsel == 2) ? (l & 15)
                         :               (l >> 4) + 4 * r;
            const int rowg = m0 + mt + i_;
            #pragma unroll
            for (int nt = 0; nt < 2; nt++) {
                const int colg = n0 + wc + nt * 16 + j_;
                qo[(size_t)rowg * Dv + colg] = acc[0][nt][r] + (double)bq[colg];
                ko[(size_t)rowg * Dv + colg] = acc[1][nt][r] + (double)bk[colg];
                vo[(size_t)rowg * Dv + colg] = acc[2][nt][r] + (double)bvv[colg];
            }
        }
    } else {
        double fac[3][8];
        #pragma unroll
        for (int z = 0; z < 3; z++)
            #pragma unroll
            for (int c = 0; c < 8; c++) fac[z][c] = 0.0;
        const int frow = mt + (l & 15);
        const int fcb  = wc + (l >> 4) * 8;
        for (int k0 = 0; k0 < Dv; k0 += 16) {
            __syncthreads();
            stage(k0);
            __syncthreads();
            #pragma unroll
            for (int kk = 0; kk < 16; kk++) {
                const double a = As[frow][kk];
                #pragma unroll
                for (int z = 0; z < 3; z++)
                    #pragma unroll
                    for (int c = 0; c < 8; c++)
                        fac[z][c] = fma(a, Bs[z][kk][fcb + c], fac[z][c]);
            }
        }
        const int rowg = m0 + frow;
        #pragma unroll
        for (int c = 0; c < 8; c++) {
            const int colg = n0 + fcb + c;
            qo[(size_t)rowg * Dv + colg] = fac[0][c] + (double)bq[colg];
            ko[(size_t)rowg * Dv + colg] = fac[1][c] + (double)bk[colg];
            vo[(size_t)rowg * Dv + colg] = fac[2][c] + (double)bvv[colg];
        }
    }
}

// ---------------- scores f64 GEMM, fused gating, split-K x2 (verified) ----------------
__launch_bounds__(256)
__global__ void scores64_k(const double* __restrict__ A0, const double* __restrict__ A1,
                           const double* __restrict__ gate, const float* __restrict__ Bm,
                           double* __restrict__ Cbase)
{
    const int M = NTOK, N = Nv, Kd = Dv;
    const int z = blockIdx.z;
    const int kbeg = z * (Dv / 2), kend = kbeg + Dv / 2;
    double* Cout = Cbase + (size_t)z * M * N;
    __shared__ double As[16][68];
    __shared__ double Bs[16][68];
    const int tid = threadIdx.x;
    const int m0 = blockIdx.y * 64, n0 = blockIdx.x * 64;
    const int tx = tid & 15, ty = tid >> 4;
    double acc[4][4] = {};
    const int lm = tid >> 2, lk4 = (tid & 3) << 2;
    for (int k0 = kbeg; k0 < kend; k0 += 16) {
        const double g0 = gate[2 * (m0 + lm)], g1 = gate[2 * (m0 + lm) + 1];
        double4 a0 = *(const double4*)(A0 + (size_t)(m0 + lm) * Kd + k0 + lk4);
        double4 a1 = *(const double4*)(A1 + (size_t)(m0 + lm) * Kd + k0 + lk4);
        As[lk4 + 0][lm] = g0 * a0.x + g1 * a1.x;
        As[lk4 + 1][lm] = g0 * a0.y + g1 * a1.y;
        As[lk4 + 2][lm] = g0 * a0.z + g1 * a1.z;
        As[lk4 + 3][lm] = g0 * a0.w + g1 * a1.w;
        const int nn = tid >> 2, kq = (tid & 3) << 2;
        float4 bv4 = *(const float4*)(Bm + (size_t)(n0 + nn) * Kd + k0 + kq);
        Bs[kq + 0][nn] = (double)bv4.x; Bs[kq + 1][nn] = (double)bv4.y;
        Bs[kq + 2][nn] = (double)bv4.z; Bs[kq + 3][nn] = (double)bv4.w;
        __syncthreads();
        #pragma unroll
        for (int kk = 0; kk < 16; kk++) {
            double a_[4], b_[4];
            *(double4*)a_ = *(const double4*)&As[kk][ty << 2];
            *(double4*)b_ = *(const double4*)&Bs[kk][tx << 2];
            #pragma unroll
            for (int i = 0; i < 4; i++)
                #pragma unroll
                for (int j = 0; j < 4; j++)
                    acc[i][j] = fma(a_[i], b_[j], acc[i][j]);
        }
        __syncthreads();
    }
    #pragma unroll
    for (int i = 0; i < 4; i++) {
        const int row = m0 + (ty << 2) + i;
        #pragma unroll
        for (int j = 0; j < 4; j++)
            Cout[(size_t)row * N + n0 + (tx << 2) + j] = acc[i][j];
    }
}

// ---------------- bf16 MFMA GEMM, 128x128 tile, BK=32, split-K via z ----------------
template<int EPI>
__launch_bounds__(256)
__global__ void mfma_k(const __hip_bfloat16* __restrict__ A, const __hip_bfloat16* __restrict__ B,
                       void* __restrict__ Cout_, int M, int N, int Kt, int kper)
{
    __shared__ __hip_bfloat16 As[128][40];
    __shared__ __hip_bfloat16 Bs[128][40];
    const int tid = threadIdx.x;
    const int m0 = blockIdx.y * 128, n0 = blockIdx.x * 128;
    const int z = blockIdx.z;
    const int kbeg = z * kper, kend = kbeg + kper;
    const int w = tid >> 6, l = tid & 63;
    const int wr = (w >> 1) * 64, wc = (w & 1) * 64;
    const int lm = l & 15, quad = l >> 4;
    float4v acc[4][4];
    #pragma unroll
    for (int i = 0; i < 4; i++)
        #pragma unroll
        for (int j = 0; j < 4; j++)
            acc[i][j] = (float4v){0.f, 0.f, 0.f, 0.f};
    const int srow = tid >> 1, skb = (tid & 1) * 16;
    for (int k0 = kbeg; k0 < kend; k0 += 32) {
        *(uint4*)&As[srow][skb]     = *(const uint4*)(A + (size_t)(m0 + srow) * Kt + k0 + skb);
        *(uint4*)&As[srow][skb + 8] = *(const uint4*)(A + (size_t)(m0 + srow) * Kt + k0 + skb + 8);
        *(uint4*)&Bs[srow][skb]     = *(const uint4*)(B + (size_t)(n0 + srow) * Kt + k0 + skb);
        *(uint4*)&Bs[srow][skb + 8] = *(const uint4*)(B + (size_t)(n0 + srow) * Kt + k0 + skb + 8);
        __syncthreads();
        short8 af[4], bf[4];
        #pragma unroll
        for (int mi = 0; mi < 4; mi++) af[mi] = *(const short8*)&As[wr + mi * 16 + lm][quad * 8];
        #pragma unroll
        for (int ni = 0; ni < 4; ni++) bf[ni] = *(const short8*)&Bs[wc + ni * 16 + lm][quad * 8];
        #pragma unroll
        for (int mi = 0; mi < 4; mi++)
            #pragma unroll
            for (int ni = 0; ni < 4; ni++)
                acc[mi][ni] = __builtin_amdgcn_mfma_f32_16x16x32_bf16(af[mi], bf[ni], acc[mi][ni], 0, 0, 0);
        __syncthreads();
    }
    #pragma unroll
    for (int mi = 0; mi < 4; mi++) {
        #pragma unroll
        for (int ni = 0; ni < 4; ni++) {
            const int col = n0 + wc + ni * 16 + lm;
            #pragma unroll
            for (int r = 0; r < 4; r++) {
                const int row = m0 + wr + mi * 16 + quad * 4 + r;
                float c = acc[mi][ni][r];
                if (EPI == 0) {
                    ((float*)Cout_)[(size_t)z * M * N + (size_t)row * N + col] = c;
                } else {
                    c = 0.5f * c * (1.0f + erff(c * 0.70710678118654752f));
                    ((__hip_bfloat16*)Cout_)[(size_t)row * N + col] = __float2bfloat16(c);
                }
            }
        }
    }
}

// ---------------- f64 flash attention, 4 KV chunks of 8 tiles ----------------
// K stored ROW-MAJOR in LDS (Ks[32][71]) — QK reads K[col][kk..kk+1] contiguously,
// so no transpose staging is needed. Pad 71 => QK loads 2-way (free), stores = Vs-style.
__device__ __constant__ int c_slotbase[4] = {0, 0, 384, 640};
__device__ __constant__ int c_cnt[4]      = {0, 24, 16, 8};

__launch_bounds__(256)
__global__ void attn64c_k(const double* __restrict__ q, const double* __restrict__ k,
                          const double* __restrict__ v, double* __restrict__ ctxun,
                          double* __restrict__ Opart, double* __restrict__ mbuf,
                          double* __restrict__ lbuf)
{
    const int qt = blockIdx.x, bh = blockIdx.y, ch = blockIdx.z;
    if (qt < ch * 8) return;
    const int b = bh >> 3, h = bh & 7;
    __shared__ double Qs[32][70];
    __shared__ double Ks[32][71];
    __shared__ double Vs[32][70];
    const int tid = threadIdx.x;
    const int r = tid >> 3, cc = tid & 7;
    const int lane = tid & 63;
    const int lbase = lane & 56;
    const size_t qoff = ((size_t)b * Sv + (size_t)qt * 32) * Dv + h * 64;
    #pragma unroll
    for (int i = 0; i < 4; i++) {
        int f = i * 256 + tid;
        int row = f >> 5, c2 = (f & 31) * 2;
        *(double2*)&Qs[row][c2] = *(const double2*)(q + qoff + (size_t)row * Dv + c2);
    }
    double O[8] = {};
    double mrun = -1e300, lrun = 0.0;
    const int iglob = qt * 32 + r;
    const int jbeg = ch * 8;
    const int jend = (qt < jbeg + 7) ? qt : (jbeg + 7);
    const int c4 = cc * 4;
    for (int jt = jbeg; jt <= jend; jt++) {
        __syncthreads();
        const size_t koff = ((size_t)b * Sv + (size_t)jt * 32) * Dv + h * 64;
        #pragma unroll
        for (int i = 0; i < 4; i++) {
            int f = i * 256 + tid;
            int row = f >> 5, c2 = (f & 31) * 2;
            *(double2*)&Ks[row][c2] = *(const double2*)(k + koff + (size_t)row * Dv + c2);
            *(double2*)&Vs[row][c2] = *(const double2*)(v + koff + (size_t)row * Dv + c2);
        }
        __syncthreads();
        double a[4] = {0.0, 0.0, 0.0, 0.0};
        #pragma unroll 8
        for (int kk = 0; kk < 64; kk += 2) {
            double2 qv = *(const double2*)&Qs[r][kk];
            double2 k0 = *(const double2*)&Ks[c4 + 0][kk];
            double2 k1 = *(const double2*)&Ks[c4 + 1][kk];
            double2 k2 = *(const double2*)&Ks[c4 + 2][kk];
            double2 k3 = *(const double2*)&Ks[c4 + 3][kk];
            a[0] = fma(qv.x, k0.x, fma(qv.y, k0.y, a[0]));
            a[1] = fma(qv.x, k1.x, fma(qv.y, k1.y, a[1]));
            a[2] = fma(qv.x, k2.x, fma(qv.y, k2.y, a[2]));
            a[3] = fma(qv.x, k3.x, fma(qv.y, k3.y, a[3]));
        }
        double p[4];
        double mx = -1e300;
        #pragma unroll
        for (int jj = 0; jj < 4; jj++) {
            const int jglob = jt * 32 + cc * 4 + jj;
            p[jj] = (jglob <= iglob) ? a[jj] * 0.125 : -1e300;
            mx = fmax(mx, p[jj]);
        }
        mx = fmax(mx, __shfl_xor(mx, 1));
        mx = fmax(mx, __shfl_xor(mx, 2));
        mx = fmax(mx, __shfl_xor(mx, 4));
        const double mnew = fmax(mrun, mx);
        double rsum = 0.0;
        #pragma unroll
        for (int jj = 0; jj < 4; jj++) { p[jj] = exp(p[jj] - mnew); rsum += p[jj]; }
        rsum += __shfl_xor(rsum, 1);
        rsum += __shfl_xor(rsum, 2);
        rsum += __shfl_xor(rsum, 4);
        const double alpha = exp(mrun - mnew);
        lrun = lrun * alpha + rsum;
        mrun = mnew;
        #pragma unroll
        for (int c = 0; c < 8; c++) O[c] *= alpha;
        #pragma unroll
        for (int jsrc = 0; jsrc < 8; jsrc++) {
            #pragma unroll
            for (int jj = 0; jj < 4; jj++) {
                const double pj = __shfl(p[jj], lbase + jsrc);
                const double* vrow = &Vs[jsrc * 4 + jj][cc * 8];
                #pragma unroll
                for (int c2 = 0; c2 < 8; c2 += 2) {
                    double2 vv = *(const double2*)&vrow[c2];
                    O[c2 + 0] = fma(pj, vv.x, O[c2 + 0]);
                    O[c2 + 1] = fma(pj, vv.y, O[c2 + 1]);
                }
            }
        }
    }
    if (cc == 0) {
        const int mi = ((bh * 32 + qt) * 4 + ch) * 32 + r;
        mbuf[mi] = mrun; lbuf[mi] = lrun;
    }
    if (ch == 0) {
        const size_t obase = ((size_t)b * Sv + (size_t)iglob) * Dv + h * 64 + cc * 8;
        #pragma unroll
        for (int c2 = 0; c2 < 8; c2 += 2) { double2 t{O[c2], O[c2+1]}; *(double2*)(ctxun + obase + c2) = t; }
    } else {
        const int slot = c_slotbase[ch] + bh * c_cnt[ch] + (qt - ch * 8);
        const size_t obase = ((size_t)slot * 32 + r) * 64 + cc * 8;
        #pragma unroll
        for (int c2 = 0; c2 < 8; c2 += 2) { double2 t{O[c2], O[c2+1]}; *(double2*)(Opart + obase + c2) = t; }
    }
}

// ---------------- merge up to 4 KV chunks (exact flash combine) ----------------
__launch_bounds__(256)
__global__ void attnmerge_k(double* __restrict__ ctx, const double* __restrict__ Opart,
                            const double* __restrict__ mbuf, const double* __restrict__ lbuf)
{
    const size_t i = (size_t)blockIdx.x * 256 + threadIdx.x;   // double2 index
    const size_t e = i * 2;
    const int d = (int)(e & 511);
    const int s = (int)((e >> 9) & 1023);
    const int b = (int)(e >> 19);
    const int h = d >> 6;
    const int qt = s >> 5, r = s & 31;
    const int bh = b * 8 + h;
    int nch = qt >> 3; if (nch > 3) nch = 3;
    const int mib = ((bh * 32 + qt) * 4) * 32 + r;
    double ms = mbuf[mib];
    for (int c = 1; c <= nch; c++) ms = fmax(ms, mbuf[mib + c * 32]);
    double2 o = *(const double2*)(ctx + e);
    double a0 = exp(mbuf[mib] - ms);
    double den = lbuf[mib] * a0;
    o.x *= a0; o.y *= a0;
    for (int c = 1; c <= nch; c++) {
        const double ac = exp(mbuf[mib + c * 32] - ms);
        den += lbuf[mib + c * 32] * ac;
        const int slot = c_slotbase[c] + bh * c_cnt[c] + (qt - c * 8);
        const size_t op = ((size_t)slot * 32 + r) * 64 + (d & 63);
        double2 oc = *(const double2*)(Opart + op);
        o.x = fma(ac, oc.x, o.x);
        o.y = fma(ac, oc.y, o.y);
    }
    const double inv = 1.0 / den;
    o.x *= inv; o.y *= inv;
    *(double2*)(ctx + e) = o;
}

// ---------------- f64 gate ----------------
__launch_bounds__(256)
__global__ void gate64_k(const double* __restrict__ normed, const double* __restrict__ ctx,
                         const float* __restrict__ Wg, const float* __restrict__ bg,
                         double* __restrict__ gate)
{
    const int wv = threadIdx.x >> 6, lane = threadIdx.x & 63;
    const int t = blockIdx.x * 4 + wv;
    double a0 = 0.0, a1 = 0.0;
    for (int d = lane; d < Dv; d += 64) {
        double nv = normed[(size_t)t * Dv + d];
        double cv = ctx[(size_t)t * Dv + d];
        a0 += nv * (double)Wg[2 * d]     + cv * (double)Wg[2 * (d + Dv)];
        a1 += nv * (double)Wg[2 * d + 1] + cv * (double)Wg[2 * (d + Dv) + 1];
    }
    #pragma unroll
    for (int off = 32; off; off >>= 1) { a0 += __shfl_xor(a0, off); a1 += __shfl_xor(a1, off); }
    if (lane == 0) {
        a0 += (double)bg[0]; a1 += (double)bg[1];
        double m = fmax(a0, a1);
        double e0 = exp(a0 - m), e1 = exp(a1 - m);
        double inv = 1.0 / (e0 + e1);
        gate[2 * t] = e0 * inv; gate[2 * t + 1] = e1 * inv;
    }
}

// ------- f64 top-k (sum of 2 score partials) + residual + tcoords + idx + fused LN2 (bf16 out) -------
__launch_bounds__(256)
__global__ void topk64_k(const double* __restrict__ s0, const float* __restrict__ x,
                         const float* __restrict__ emb, const float* __restrict__ coords,
                         const float* __restrict__ g2, const float* __restrict__ b2,
                         float* __restrict__ x2, __hip_bfloat16* __restrict__ normed2bf,
                         float* __restrict__ tcoords, float* __restrict__ idx_out)
{
    __shared__ double sc[4][Nv];
    const int wv = threadIdx.x >> 6, lane = threadIdx.x & 63;
    const int t = blockIdx.x * 4 + wv;
    const double* s1 = s0 + (size_t)NTOK * Nv;
    double* s = sc[wv];
    #pragma unroll
    for (int i = 0; i < 8; i++) {
        const size_t idx = (size_t)t * Nv + i * 64 + lane;
        s[i * 64 + lane] = s0[idx] + s1[idx];
    }
    __syncthreads();
    double wval[Kv]; int widx[Kv];
    for (int kk = 0; kk < Kv; kk++) {
        double bvv = -1e300; int bi = Nv;
        #pragma unroll
        for (int i = 0; i < 8; i++) {
            const int d = lane * 8 + i;
            const double vv = s[d];
            if (vv > bvv) { bvv = vv; bi = d; }
        }
        #pragma unroll
        for (int off = 1; off < 64; off <<= 1) {
            double ov = __shfl_xor(bvv, off);
            int    oi = __shfl_xor(bi, off);
            if (ov > bvv || (ov == bvv && oi < bi)) { bvv = ov; bi = oi; }
        }
        wval[kk] = bvv; widx[kk] = bi;
        __syncthreads();
        if (lane == (bi >> 3)) s[bi] = -1e301;
        __syncthreads();
        if (lane == kk) idx_out[(size_t)t * Kv + kk] = (float)bi;
    }
    double w[Kv]; double sum = 0.0;
    #pragma unroll
    for (int kk = 0; kk < Kv; kk++) { w[kk] = exp(wval[kk] - wval[0]); sum += w[kk]; }
    const double invs = 1.0 / sum;
    #pragma unroll
    for (int kk = 0; kk < Kv; kk++) w[kk] *= invs;
    float xv[8];
    float sm = 0.0f, sq = 0.0f;
    #pragma unroll
    for (int i = 0; i < 8; i++) {
        const int d = lane + 64 * i;
        double info = 0.0;
        #pragma unroll
        for (int kk = 0; kk < Kv; kk++)
            info = fma(w[kk], (double)emb[(size_t)widx[kk] * Dv + d], info);
        float vv = (float)((double)x[(size_t)t * Dv + d] + info);
        xv[i] = vv;
        x2[(size_t)t * Dv + d] = vv;
        sm += vv; sq += vv * vv;
    }
    #pragma unroll
    for (int off = 32; off; off >>= 1) { sm += __shfl_xor(sm, off); sq += __shfl_xor(sq, off); }
    const float mu = sm * (1.0f / Dv);
    const float var = sq * (1.0f / Dv) - mu * mu;
    const float rstd = rsqrtf(var + 1e-5f);
    #pragma unroll
    for (int i = 0; i < 8; i++) {
        const int d = lane + 64 * i;
        normed2bf[(size_t)t * Dv + d] = __float2bfloat16((xv[i] - mu) * rstd * g2[d] + b2[d]);
    }
    if (lane < NBv) {
        double tc = 0.0;
        #pragma unroll
        for (int kk = 0; kk < Kv; kk++)
            tc = fma(w[kk], (double)coords[(size_t)widx[kk] * NBv + lane], tc);
        tcoords[t * NBv + lane] = (float)tc;
    }
}

// ---------------- basis_A -> AcatT bf16 [nc][d] ----------------
__launch_bounds__(256)
__global__ void acatbf_k(const float* __restrict__ bA, __hip_bfloat16* __restrict__ AcatT)
{
    const int i = blockIdx.x * 256 + threadIdx.x;   // < 262144
    const int d = i & 511, nc = i >> 9;
    const int n = nc >> 6, r = nc & 63;
    AcatT[i] = __float2bfloat16(bA[n * 32768 + d * 64 + r]);
}

// ---------------- tiled transpose + f32->bf16: in [R][C] -> out [C][R] ----------------
__launch_bounds__(256)
__global__ void tr2bf_k(const float* __restrict__ in, __hip_bfloat16* __restrict__ out,
                        int R, int C)
{
    __shared__ float tile[32][33];
    const int c0 = blockIdx.x * 32, r0 = blockIdx.y * 32;
    const int tx = threadIdx.x & 31, ty = threadIdx.x >> 5;   // ty in 0..7
    #pragma unroll
    for (int i = 0; i < 4; i++)
        tile[ty + 8 * i][tx] = in[(size_t)(r0 + ty + 8 * i) * C + c0 + tx];
    __syncthreads();
    #pragma unroll
    for (int i = 0; i < 4; i++)
        out[(size_t)(c0 + ty + 8 * i) * R + r0 + tx] = __float2bfloat16(tile[tx][ty + 8 * i]);
}

// ---------------- combine: sum 4 G partials; h = sum_n c_n G_n ; u = c ⊗ h (bf16 out) ----------------
__launch_bounds__(256)
__global__ void combine_k(const float* __restrict__ Gp, const float* __restrict__ tcoords,
                          __hip_bfloat16* __restrict__ u_bf)
{
    const size_t M1 = (size_t)NTOK * Dv;
    const int wv = threadIdx.x >> 6, lane = threadIdx.x & 63;
    const int t = blockIdx.x * 4 + wv;
    float cs[NBv];
    #pragma unroll
    for (int n = 0; n < NBv; n++) cs[n] = tcoords[t * NBv + n];
    float h = 0.0f;
    #pragma unroll
    for (int n = 0; n < NBv; n++) {
        const size_t gi = (size_t)t * Dv + n * 64 + lane;
        float g = Gp[gi] + Gp[gi + M1] + Gp[gi + 2 * M1] + Gp[gi + 3 * M1];
        h = fmaf(cs[n], g, h);
    }
    #pragma unroll
    for (int n = 0; n < NBv; n++)
        u_bf[(size_t)t * Dv + n * 64 + lane] = __float2bfloat16(cs[n] * h);
}

// ---------------- reduce 4 split-K partials + bias + residual ----------------
__launch_bounds__(256)
__global__ void reduce4_k(const float* __restrict__ p4, const float* __restrict__ bd,
                          const float* __restrict__ x2, float* __restrict__ xout)
{
    const size_t M1 = (size_t)NTOK * Dv;
    const size_t i = (size_t)blockIdx.x * 256 + threadIdx.x;
    float c = p4[i] + p4[i + M1] + p4[i + 2 * M1] + p4[i + 3 * M1];
    xout[i] = c + bd[i & 511] + x2[i];
}

extern "C" void kernel_launch(void* const* d_in, const int* in_sizes, int n_in,
                              void* d_out, int out_size, void* d_ws, size_t ws_size,
                              hipStream_t stream) {
    (void)in_sizes; (void)n_in; (void)out_size; (void)ws_size;
    const size_t M1 = (size_t)NTOK * Dv;

    const float* x   = (const float*)d_in[0];
    const float* emb = (const float*)d_in[1];
    const float* Wq  = (const float*)d_in[2];
    const float* bq  = (const float*)d_in[3];
    const float* Wk  = (const float*)d_in[4];
    const float* bk  = (const float*)d_in[5];
    const float* Wv  = (const float*)d_in[6];
    const float* bvv = (const float*)d_in[7];
    const float* Wg  = (const float*)d_in[8];
    const float* bg  = (const float*)d_in[9];
    const float* bA  = (const float*)d_in[10];
    const float* bB  = (const float*)d_in[11];
    const float* crd = (const float*)d_in[12];
    const float* Wd  = (const float*)d_in[13];
    const float* bd  = (const float*)d_in[14];
    const float* l1g = (const float*)d_in[15];
    const float* l1b = (const float*)d_in[16];
    const float* l2g = (const float*)d_in[17];
    const float* l2b = (const float*)d_in[18];
    // d_in[19] = mask: causal tril, never read.

    double* normed64 = (double*)d_ws;                  // M1 d (8 MB)
    double* q64      = normed64 + M1;                  // M1 d
    double* k64      = q64 + M1;                       // M1 d
    double* v64      = k64 + M1;                       // M1 d
    double* ctx64    = v64 + M1;                       // M1 d
    double* Opart    = ctx64 + M1;                     // 1,572,864 d (12.58 MB)
    double* mbuf     = Opart + 1572864;                // 65536 d
    double* lbuf     = mbuf + 65536;                   // 65536 d
    double* gate64   = lbuf + 65536;                   // 4096 d
    float*  tcoords  = (float*)(gate64 + 4096);        // 16384 f
    __hip_bfloat16* AcatT = (__hip_bfloat16*)(tcoords + 16384);   // 262144 bf16

    // overlays
    double* s0 = q64;                                  // + s1 = k64 (contiguous)
    float*  x2 = (float*)v64;                          // M1 f (first 4 MB of v64)
    __hip_bfloat16* normed2bf = (__hip_bfloat16*)(x2 + M1);       // 2 MB
    __hip_bfloat16* u_bf      = normed2bf + M1;                   // 2 MB (v64 = 8 MB total)
    float* Gp = (float*)q64;                           // 4*M1 f over q64+k64
    float* p4 = (float*)q64;                           // reuse after Gp dead
    __hip_bfloat16* hf_bf = (__hip_bfloat16*)Opart;    // 4*M1 bf16 (8 MB)
    __hip_bfloat16* bBT   = hf_bf + 4 * M1;            // 2 MB
    __hip_bfloat16* WdT   = bBT + M1;                  // 2 MB   (total 12.5 <= 12.58 MB)

    float* xout    = (float*)d_out;
    float* idx_out = (float*)d_out + M1;

    ln64_k<<<NTOK, 256, 0, stream>>>(x, l1g, l1b, normed64);
    qkvMC_k<<<dim3(8, 64), 256, 0, stream>>>(normed64, Wq, Wk, Wv, bq, bk, bvv, q64, k64, v64);
    attn64c_k<<<dim3(32, 16, 4), 256, 0, stream>>>(q64, k64, v64, ctx64, Opart, mbuf, lbuf);
    attnmerge_k<<<(int)(M1 / 512), 256, 0, stream>>>(ctx64, Opart, mbuf, lbuf);
    gate64_k<<<NTOK / 4, 256, 0, stream>>>(normed64, ctx64, Wg, bg, gate64);
    scores64_k<<<dim3(8, 32, 2), 256, 0, stream>>>(normed64, ctx64, gate64, emb, s0);
    topk64_k<<<NTOK / 4, 256, 0, stream>>>(s0, x, emb, crd, l2g, l2b, x2, normed2bf, tcoords, idx_out);
    // weight preps (Opart dead after merge; s0 dead after topk)
    acatbf_k<<<1024, 256, 0, stream>>>(bA, AcatT);
    tr2bf_k<<<dim3(DFv / 32, Dv / 32), 256, 0, stream>>>(bB, bBT, Dv, DFv);   // bB [512][2048] -> [2048][512]
    tr2bf_k<<<dim3(Dv / 32, DFv / 32), 256, 0, stream>>>(Wd, WdT, DFv, Dv);   // Wd [2048][512] -> [512][2048]
    // G partials: normed2 @ Acat [2048x512x512] bf16 MFMA, split-K x4
    mfma_k<0><<<dim3(4, 16, 4), 256, 0, stream>>>(normed2bf, AcatT, Gp, NTOK, Dv, Dv, Dv / 4);
    combine_k<<<NTOK / 4, 256, 0, stream>>>(Gp, tcoords, u_bf);
    // hf = gelu(u @ bB) [2048x2048x512] bf16 MFMA
    mfma_k<1><<<dim3(16, 16, 1), 256, 0, stream>>>(u_bf, bBT, hf_bf, NTOK, DFv, Dv, Dv);
    // out partials: hf @ Wd [2048x512x2048] bf16 MFMA, split-K x4
    mfma_k<0><<<dim3(4, 16, 4), 256, 0, stream>>>(hf_bf, WdT, p4, NTOK, Dv, DFv, DFv / 4);
    reduce4_k<<<(int)(M1 / 256), 256, 0, stream>>>(p4, bd, x2, xout);
}

// Round 8
// 609.892 us; speedup vs baseline: 1.1131x; 1.1131x over previous
//
#include <hip/hip_runtime.h>
#include <hip/hip_bf16.h>

#define Bv 2
#define Sv 1024
#define Dv 512
#define Hv 8
#define Nv 512
#define Kv 16
#define NBv 8
#define DFv 2048
#define NTOK (Bv*Sv)   // 2048

typedef __attribute__((ext_vector_type(8))) short short8;
typedef __attribute__((ext_vector_type(4))) float float4v;
typedef __attribute__((ext_vector_type(4))) double dbl4;

// ---- fast f64 exp: range-reduced Taylor-13, ~1ulp, exp(x<=-708) -> 0 (proven r6) ----
__device__ __forceinline__ double fexp64(double x)
{
    if (x < -708.0) return 0.0;
    const double SHIFT = 6755399441055744.0;            // 1.5 * 2^52
    double t  = fma(x, 1.4426950408889634074, SHIFT);
    double nd = t - SHIFT;                              // round(x * log2(e))
    double r  = fma(-nd, 6.93147180369123816490e-01, x);
    r         = fma(-nd, 1.90821492927058770002e-10, r);
    double p = 1.0 / 6227020800.0;                      // 1/13!
    p = fma(p, r, 1.0 / 479001600.0);
    p = fma(p, r, 1.0 / 39916800.0);
    p = fma(p, r, 1.0 / 3628800.0);
    p = fma(p, r, 1.0 / 362880.0);
    p = fma(p, r, 1.0 / 40320.0);
    p = fma(p, r, 1.0 / 5040.0);
    p = fma(p, r, 1.0 / 720.0);
    p = fma(p, r, 1.0 / 120.0);
    p = fma(p, r, 1.0 / 24.0);
    p = fma(p, r, 1.0 / 6.0);
    p = fma(p, r, 0.5);
    p = fma(p, r, 1.0);
    p = fma(p, r, 1.0);
    long long ni = (long long)nd;                       // in [-1022, 0]
    double s = __longlong_as_double((unsigned long long)(ni + 1023) << 52);
    return p * s;
}

// ---------------- LayerNorm f64 (f32 in / f64 out) ----------------
__launch_bounds__(256)
__global__ void ln64_k(const float* __restrict__ x, const float* __restrict__ g,
                       const float* __restrict__ b, double* __restrict__ out)
{
    const int t = blockIdx.x;
    const size_t base = (size_t)t * Dv;
    const int tid = threadIdx.x;
    double v0 = (double)x[base + tid];
    double v1 = (double)x[base + tid + 256];
    double s = v0 + v1, ss = v0 * v0 + v1 * v1;
    #pragma unroll
    for (int off = 32; off; off >>= 1) { s += __shfl_xor(s, off); ss += __shfl_xor(ss, off); }
    __shared__ double red[4][2];
    const int wv = tid >> 6, ln = tid & 63;
    if (ln == 0) { red[wv][0] = s; red[wv][1] = ss; }
    __syncthreads();
    s  = red[0][0] + red[1][0] + red[2][0] + red[3][0];
    ss = red[0][1] + red[1][1] + red[2][1] + red[3][1];
    double mu  = s * (1.0 / Dv);
    double var = ss * (1.0 / Dv) - mu * mu;
    double rstd = 1.0 / sqrt(var + 1e-5);
    out[base + tid]       = (v0 - mu) * rstd * (double)g[tid]       + (double)b[tid];
    out[base + tid + 256] = (v1 - mu) * rstd * (double)g[tid + 256] + (double)b[tid + 256];
}

// ---------------- fused QKV f64 GEMM, self-calibrating MFMA with scalar fallback ----------------
__launch_bounds__(256)
__global__ void qkvMC_k(const double* __restrict__ A,
                        const float* __restrict__ Wq, const float* __restrict__ Wk,
                        const float* __restrict__ Wv, const float* __restrict__ bq,
                        const float* __restrict__ bk, const float* __restrict__ bvv,
                        double* __restrict__ qo, double* __restrict__ ko,
                        double* __restrict__ vo)
{
    __shared__ double As[32][18];
    __shared__ double Bs[3][16][66];
    const int tid = threadIdx.x;
    const int n0 = blockIdx.x * 64, m0 = blockIdx.y * 32;
    const int w = tid >> 6, l = tid & 63;
    const int mt = (w >> 1) * 16, wc = (w & 1) * 32;
    const int ar = tid >> 3, ak = (tid & 7) * 2;
    const int bkk = tid >> 4, bn = (tid & 15) * 4;

    // ---- runtime layout probe (exact small-int arithmetic) ----
    int rA = 0, kA = 0, kB = 0, cB = 0, dsel = -1;
    #pragma unroll 1
    for (int ab = 0; ab < 4; ab++) {
        if (dsel >= 0) break;
        const int a_ = ab & 1, b_ = ab >> 1;
        const int rA_ = a_ ? (l >> 2) : (l & 15);
        const int kA_ = a_ ? (l & 3)  : (l >> 4);
        const int kB_ = b_ ? (l & 3)  : (l >> 4);
        const int cB_ = b_ ? (l >> 2) : (l & 15);
        const double av  = (double)(((rA_ * 37 + kA_ * 11) % 19) + 1);
        const double bvp = (double)(((kB_ * 23 + cB_ * 7) % 17) + 1);
        dbl4 dd = __builtin_amdgcn_mfma_f64_16x16x4f64(av, bvp, (dbl4){0.0, 0.0, 0.0, 0.0}, 0, 0, 0);
        #pragma unroll 1
        for (int d = 0; d < 4; d++) {
            if (dsel >= 0) break;
            int okv = 1;
            #pragma unroll
            for (int r = 0; r < 4; r++) {
                const int i_ = (d == 0) ? 4 * (l >> 4) + r
                             : (d == 1) ? (l & 15)
                             : (d == 2) ? (l >> 4) + 4 * r
                             :            (l & 15);
                const int j_ = (d == 0) ? (l & 15)
                             : (d == 1) ? 4 * (l >> 4) + r
                             : (d == 2) ? (l & 15)
                             :            (l >> 4) + 4 * r;
                double e = 0.0;
                #pragma unroll
                for (int kk2 = 0; kk2 < 4; kk2++)
                    e += (double)(((i_ * 37 + kk2 * 11) % 19) + 1)
                       * (double)(((kk2 * 23 + j_ * 7) % 17) + 1);
                okv &= (dd[r] == e) ? 1 : 0;
            }
            if (__all(okv)) { dsel = d; rA = rA_; kA = kA_; kB = kB_; cB = cB_; }
        }
    }

    auto stage = [&](int k0) {
        double2 avv = *(const double2*)(A + (size_t)(m0 + ar) * Dv + k0 + ak);
        *(double2*)&As[ar][ak] = avv;
        {
            float4 b4 = *(const float4*)(Wq + (size_t)(k0 + bkk) * Dv + n0 + bn);
            Bs[0][bkk][bn] = (double)b4.x; Bs[0][bkk][bn + 1] = (double)b4.y;
            Bs[0][bkk][bn + 2] = (double)b4.z; Bs[0][bkk][bn + 3] = (double)b4.w;
        }
        {
            float4 b4 = *(const float4*)(Wk + (size_t)(k0 + bkk) * Dv + n0 + bn);
            Bs[1][bkk][bn] = (double)b4.x; Bs[1][bkk][bn + 1] = (double)b4.y;
            Bs[1][bkk][bn + 2] = (double)b4.z; Bs[1][bkk][bn + 3] = (double)b4.w;
        }
        {
            float4 b4 = *(const float4*)(Wv + (size_t)(k0 + bkk) * Dv + n0 + bn);
            Bs[2][bkk][bn] = (double)b4.x; Bs[2][bkk][bn + 1] = (double)b4.y;
            Bs[2][bkk][bn + 2] = (double)b4.z; Bs[2][bkk][bn + 3] = (double)b4.w;
        }
    };

    if (dsel >= 0) {
        dbl4 acc[3][2];
        #pragma unroll
        for (int z = 0; z < 3; z++)
            #pragma unroll
            for (int nt = 0; nt < 2; nt++)
                acc[z][nt] = (dbl4){0.0, 0.0, 0.0, 0.0};
        for (int k0 = 0; k0 < Dv; k0 += 16) {
            __syncthreads();
            stage(k0);
            __syncthreads();
            #pragma unroll
            for (int s = 0; s < 4; s++) {
                const double aA = As[mt + rA][4 * s + kA];
                #pragma unroll
                for (int z = 0; z < 3; z++) {
                    const double b0 = Bs[z][4 * s + kB][wc + cB];
                    const double b1 = Bs[z][4 * s + kB][wc + 16 + cB];
                    acc[z][0] = __builtin_amdgcn_mfma_f64_16x16x4f64(aA, b0, acc[z][0], 0, 0, 0);
                    acc[z][1] = __builtin_amdgcn_mfma_f64_16x16x4f64(aA, b1, acc[z][1], 0, 0, 0);
                }
            }
        }
        #pragma unroll
        for (int r = 0; r < 4; r++) {
            const int i_ = (dsel == 0) ? 4 * (l >> 4) + r
                         : (dsel == 1) ? (l & 15)
                         : (dsel == 2) ? (l >> 4) + 4 * r
                         :               (l & 15);
            const int j_ = (dsel == 0) ? (l & 15)
                         : (dsel == 1) ? 4 * (l >> 4) + r
                         : (dsel == 2) ? (l & 15)
                         :               (l >> 4) + 4 * r;
            const int rowg = m0 + mt + i_;
            #pragma unroll
            for (int nt = 0; nt < 2; nt++) {
                const int colg = n0 + wc + nt * 16 + j_;
                qo[(size_t)rowg * Dv + colg] = acc[0][nt][r] + (double)bq[colg];
                ko[(size_t)rowg * Dv + colg] = acc[1][nt][r] + (double)bk[colg];
                vo[(size_t)rowg * Dv + colg] = acc[2][nt][r] + (double)bvv[colg];
            }
        }
    } else {
        double fac[3][8];
        #pragma unroll
        for (int z = 0; z < 3; z++)
            #pragma unroll
            for (int c = 0; c < 8; c++) fac[z][c] = 0.0;
        const int frow = mt + (l & 15);
        const int fcb  = wc + (l >> 4) * 8;
        for (int k0 = 0; k0 < Dv; k0 += 16) {
            __syncthreads();
            stage(k0);
            __syncthreads();
            #pragma unroll
            for (int kk = 0; kk < 16; kk++) {
                const double a = As[frow][kk];
                #pragma unroll
                for (int z = 0; z < 3; z++)
                    #pragma unroll
                    for (int c = 0; c < 8; c++)
                        fac[z][c] = fma(a, Bs[z][kk][fcb + c], fac[z][c]);
            }
        }
        const int rowg = m0 + frow;
        #pragma unroll
        for (int c = 0; c < 8; c++) {
            const int colg = n0 + fcb + c;
            qo[(size_t)rowg * Dv + colg] = fac[0][c] + (double)bq[colg];
            ko[(size_t)rowg * Dv + colg] = fac[1][c] + (double)bk[colg];
            vo[(size_t)rowg * Dv + colg] = fac[2][c] + (double)bvv[colg];
        }
    }
}

// ---------------- scores f64 GEMM, fused gating, split-K x2 (verified) ----------------
__launch_bounds__(256)
__global__ void scores64_k(const double* __restrict__ A0, const double* __restrict__ A1,
                           const double* __restrict__ gate, const float* __restrict__ Bm,
                           double* __restrict__ Cbase)
{
    const int M = NTOK, N = Nv, Kd = Dv;
    const int z = blockIdx.z;
    const int kbeg = z * (Dv / 2), kend = kbeg + Dv / 2;
    double* Cout = Cbase + (size_t)z * M * N;
    __shared__ double As[16][68];
    __shared__ double Bs[16][68];
    const int tid = threadIdx.x;
    const int m0 = blockIdx.y * 64, n0 = blockIdx.x * 64;
    const int tx = tid & 15, ty = tid >> 4;
    double acc[4][4] = {};
    const int lm = tid >> 2, lk4 = (tid & 3) << 2;
    for (int k0 = kbeg; k0 < kend; k0 += 16) {
        const double g0 = gate[2 * (m0 + lm)], g1 = gate[2 * (m0 + lm) + 1];
        double4 a0 = *(const double4*)(A0 + (size_t)(m0 + lm) * Kd + k0 + lk4);
        double4 a1 = *(const double4*)(A1 + (size_t)(m0 + lm) * Kd + k0 + lk4);
        As[lk4 + 0][lm] = g0 * a0.x + g1 * a1.x;
        As[lk4 + 1][lm] = g0 * a0.y + g1 * a1.y;
        As[lk4 + 2][lm] = g0 * a0.z + g1 * a1.z;
        As[lk4 + 3][lm] = g0 * a0.w + g1 * a1.w;
        const int nn = tid >> 2, kq = (tid & 3) << 2;
        float4 bv4 = *(const float4*)(Bm + (size_t)(n0 + nn) * Kd + k0 + kq);
        Bs[kq + 0][nn] = (double)bv4.x; Bs[kq + 1][nn] = (double)bv4.y;
        Bs[kq + 2][nn] = (double)bv4.z; Bs[kq + 3][nn] = (double)bv4.w;
        __syncthreads();
        #pragma unroll
        for (int kk = 0; kk < 16; kk++) {
            double a_[4], b_[4];
            *(double4*)a_ = *(const double4*)&As[kk][ty << 2];
            *(double4*)b_ = *(const double4*)&Bs[kk][tx << 2];
            #pragma unroll
            for (int i = 0; i < 4; i++)
                #pragma unroll
                for (int j = 0; j < 4; j++)
                    acc[i][j] = fma(a_[i], b_[j], acc[i][j]);
        }
        __syncthreads();
    }
    #pragma unroll
    for (int i = 0; i < 4; i++) {
        const int row = m0 + (ty << 2) + i;
        #pragma unroll
        for (int j = 0; j < 4; j++)
            Cout[(size_t)row * N + n0 + (tx << 2) + j] = acc[i][j];
    }
}

// ---------------- bf16 MFMA GEMM, 128x128 tile, BK=32, split-K via z ----------------
template<int EPI>
__launch_bounds__(256)
__global__ void mfma_k(const __hip_bfloat16* __restrict__ A, const __hip_bfloat16* __restrict__ B,
                       void* __restrict__ Cout_, int M, int N, int Kt, int kper)
{
    __shared__ __hip_bfloat16 As[128][40];
    __shared__ __hip_bfloat16 Bs[128][40];
    const int tid = threadIdx.x;
    const int m0 = blockIdx.y * 128, n0 = blockIdx.x * 128;
    const int z = blockIdx.z;
    const int kbeg = z * kper, kend = kbeg + kper;
    const int w = tid >> 6, l = tid & 63;
    const int wr = (w >> 1) * 64, wc = (w & 1) * 64;
    const int lm = l & 15, quad = l >> 4;
    float4v acc[4][4];
    #pragma unroll
    for (int i = 0; i < 4; i++)
        #pragma unroll
        for (int j = 0; j < 4; j++)
            acc[i][j] = (float4v){0.f, 0.f, 0.f, 0.f};
    const int srow = tid >> 1, skb = (tid & 1) * 16;
    for (int k0 = kbeg; k0 < kend; k0 += 32) {
        *(uint4*)&As[srow][skb]     = *(const uint4*)(A + (size_t)(m0 + srow) * Kt + k0 + skb);
        *(uint4*)&As[srow][skb + 8] = *(const uint4*)(A + (size_t)(m0 + srow) * Kt + k0 + skb + 8);
        *(uint4*)&Bs[srow][skb]     = *(const uint4*)(B + (size_t)(n0 + srow) * Kt + k0 + skb);
        *(uint4*)&Bs[srow][skb + 8] = *(const uint4*)(B + (size_t)(n0 + srow) * Kt + k0 + skb + 8);
        __syncthreads();
        short8 af[4], bf[4];
        #pragma unroll
        for (int mi = 0; mi < 4; mi++) af[mi] = *(const short8*)&As[wr + mi * 16 + lm][quad * 8];
        #pragma unroll
        for (int ni = 0; ni < 4; ni++) bf[ni] = *(const short8*)&Bs[wc + ni * 16 + lm][quad * 8];
        #pragma unroll
        for (int mi = 0; mi < 4; mi++)
            #pragma unroll
            for (int ni = 0; ni < 4; ni++)
                acc[mi][ni] = __builtin_amdgcn_mfma_f32_16x16x32_bf16(af[mi], bf[ni], acc[mi][ni], 0, 0, 0);
        __syncthreads();
    }
    #pragma unroll
    for (int mi = 0; mi < 4; mi++) {
        #pragma unroll
        for (int ni = 0; ni < 4; ni++) {
            const int col = n0 + wc + ni * 16 + lm;
            #pragma unroll
            for (int r = 0; r < 4; r++) {
                const int row = m0 + wr + mi * 16 + quad * 4 + r;
                float c = acc[mi][ni][r];
                if (EPI == 0) {
                    ((float*)Cout_)[(size_t)z * M * N + (size_t)row * N + col] = c;
                } else {
                    c = 0.5f * c * (1.0f + erff(c * 0.70710678118654752f));
                    ((__hip_bfloat16*)Cout_)[(size_t)row * N + col] = __float2bfloat16(c);
                }
            }
        }
    }
}

// ---------------- f64 flash attention, 4 KV chunks of 8 tiles (r5-verified layout) ----------------
__device__ __constant__ int c_slotbase[4] = {0, 0, 384, 640};
__device__ __constant__ int c_cnt[4]      = {0, 24, 16, 8};

__launch_bounds__(256)
__global__ void attn64c_k(const double* __restrict__ q, const double* __restrict__ k,
                          const double* __restrict__ v, double* __restrict__ ctxun,
                          double* __restrict__ Opart, double* __restrict__ mbuf,
                          double* __restrict__ lbuf)
{
    const int qt = blockIdx.x, bh = blockIdx.y, ch = blockIdx.z;
    if (qt < ch * 8) return;
    const int b = bh >> 3, h = bh & 7;
    __shared__ double Qs[32][70];
    __shared__ double Kt[64][34];
    __shared__ double Vs[32][70];
    const int tid = threadIdx.x;
    const int r = tid >> 3, cc = tid & 7;
    const int lane = tid & 63;
    const int lbase = lane & 56;
    const size_t qoff = ((size_t)b * Sv + (size_t)qt * 32) * Dv + h * 64;
    #pragma unroll
    for (int i = 0; i < 4; i++) {
        int f = i * 256 + tid;
        int row = f >> 5, c2 = (f & 31) * 2;
        *(double2*)&Qs[row][c2] = *(const double2*)(q + qoff + (size_t)row * Dv + c2);
    }
    double O[8] = {};
    double mrun = -1e300, lrun = 0.0;
    const int iglob = qt * 32 + r;
    const int jbeg = ch * 8;
    const int jend = (qt < jbeg + 7) ? qt : (jbeg + 7);
    for (int jt = jbeg; jt <= jend; jt++) {
        __syncthreads();
        const size_t koff = ((size_t)b * Sv + (size_t)jt * 32) * Dv + h * 64;
        #pragma unroll
        for (int i = 0; i < 4; i++) {
            int f = i * 256 + tid;
            int row = f >> 5, c2 = (f & 31) * 2;
            double2 kv = *(const double2*)(k + koff + (size_t)row * Dv + c2);
            Kt[c2][row]     = kv.x;
            Kt[c2 + 1][row] = kv.y;
            *(double2*)&Vs[row][c2] = *(const double2*)(v + koff + (size_t)row * Dv + c2);
        }
        __syncthreads();
        double a[4] = {0.0, 0.0, 0.0, 0.0};
        #pragma unroll 8
        for (int kk = 0; kk < 64; kk += 2) {
            double2 qv  = *(const double2*)&Qs[r][kk];
            double2 ka0 = *(const double2*)&Kt[kk][cc * 4];
            double2 ka1 = *(const double2*)&Kt[kk][cc * 4 + 2];
            double2 kb0 = *(const double2*)&Kt[kk + 1][cc * 4];
            double2 kb1 = *(const double2*)&Kt[kk + 1][cc * 4 + 2];
            a[0] = fma(qv.x, ka0.x, fma(qv.y, kb0.x, a[0]));
            a[1] = fma(qv.x, ka0.y, fma(qv.y, kb0.y, a[1]));
            a[2] = fma(qv.x, ka1.x, fma(qv.y, kb1.x, a[2]));
            a[3] = fma(qv.x, ka1.y, fma(qv.y, kb1.y, a[3]));
        }
        double p[4];
        double mx = -1e300;
        #pragma unroll
        for (int jj = 0; jj < 4; jj++) {
            const int jglob = jt * 32 + cc * 4 + jj;
            p[jj] = (jglob <= iglob) ? a[jj] * 0.125 : -1e300;
            mx = fmax(mx, p[jj]);
        }
        mx = fmax(mx, __shfl_xor(mx, 1));
        mx = fmax(mx, __shfl_xor(mx, 2));
        mx = fmax(mx, __shfl_xor(mx, 4));
        const double mnew = fmax(mrun, mx);
        double rsum = 0.0;
        #pragma unroll
        for (int jj = 0; jj < 4; jj++) { p[jj] = fexp64(p[jj] - mnew); rsum += p[jj]; }
        rsum += __shfl_xor(rsum, 1);
        rsum += __shfl_xor(rsum, 2);
        rsum += __shfl_xor(rsum, 4);
        const double alpha = fexp64(mrun - mnew);
        lrun = lrun * alpha + rsum;
        mrun = mnew;
        #pragma unroll
        for (int c = 0; c < 8; c++) O[c] *= alpha;
        #pragma unroll
        for (int jsrc = 0; jsrc < 8; jsrc++) {
            #pragma unroll
            for (int jj = 0; jj < 4; jj++) {
                const double pj = __shfl(p[jj], lbase + jsrc);
                const double* vrow = &Vs[jsrc * 4 + jj][cc * 8];
                #pragma unroll
                for (int c2 = 0; c2 < 8; c2 += 2) {
                    double2 vv = *(const double2*)&vrow[c2];
                    O[c2 + 0] = fma(pj, vv.x, O[c2 + 0]);
                    O[c2 + 1] = fma(pj, vv.y, O[c2 + 1]);
                }
            }
        }
    }
    if (cc == 0) {
        const int mi = ((bh * 32 + qt) * 4 + ch) * 32 + r;
        mbuf[mi] = mrun; lbuf[mi] = lrun;
    }
    if (ch == 0) {
        const size_t obase = ((size_t)b * Sv + (size_t)iglob) * Dv + h * 64 + cc * 8;
        #pragma unroll
        for (int c2 = 0; c2 < 8; c2 += 2) { double2 t{O[c2], O[c2+1]}; *(double2*)(ctxun + obase + c2) = t; }
    } else {
        const int slot = c_slotbase[ch] + bh * c_cnt[ch] + (qt - ch * 8);
        const size_t obase = ((size_t)slot * 32 + r) * 64 + cc * 8;
        #pragma unroll
        for (int c2 = 0; c2 < 8; c2 += 2) { double2 t{O[c2], O[c2+1]}; *(double2*)(Opart + obase + c2) = t; }
    }
}

// ---------------- merge up to 4 KV chunks (exact flash combine) ----------------
__launch_bounds__(256)
__global__ void attnmerge_k(double* __restrict__ ctx, const double* __restrict__ Opart,
                            const double* __restrict__ mbuf, const double* __restrict__ lbuf)
{
    const size_t i = (size_t)blockIdx.x * 256 + threadIdx.x;   // double2 index
    const size_t e = i * 2;
    const int d = (int)(e & 511);
    const int s = (int)((e >> 9) & 1023);
    const int b = (int)(e >> 19);
    const int h = d >> 6;
    const int qt = s >> 5, r = s & 31;
    const int bh = b * 8 + h;
    int nch = qt >> 3; if (nch > 3) nch = 3;
    const int mib = ((bh * 32 + qt) * 4) * 32 + r;
    double ms = mbuf[mib];
    for (int c = 1; c <= nch; c++) ms = fmax(ms, mbuf[mib + c * 32]);
    double2 o = *(const double2*)(ctx + e);
    double a0 = exp(mbuf[mib] - ms);
    double den = lbuf[mib] * a0;
    o.x *= a0; o.y *= a0;
    for (int c = 1; c <= nch; c++) {
        const double ac = exp(mbuf[mib + c * 32] - ms);
        den += lbuf[mib + c * 32] * ac;
        const int slot = c_slotbase[c] + bh * c_cnt[c] + (qt - c * 8);
        const size_t op = ((size_t)slot * 32 + r) * 64 + (d & 63);
        double2 oc = *(const double2*)(Opart + op);
        o.x = fma(ac, oc.x, o.x);
        o.y = fma(ac, oc.y, o.y);
    }
    const double inv = 1.0 / den;
    o.x *= inv; o.y *= inv;
    *(double2*)(ctx + e) = o;
}

// ---------------- f64 gate ----------------
__launch_bounds__(256)
__global__ void gate64_k(const double* __restrict__ normed, const double* __restrict__ ctx,
                         const float* __restrict__ Wg, const float* __restrict__ bg,
                         double* __restrict__ gate)
{
    const int wv = threadIdx.x >> 6, lane = threadIdx.x & 63;
    const int t = blockIdx.x * 4 + wv;
    double a0 = 0.0, a1 = 0.0;
    for (int d = lane; d < Dv; d += 64) {
        double nv = normed[(size_t)t * Dv + d];
        double cv = ctx[(size_t)t * Dv + d];
        a0 += nv * (double)Wg[2 * d]     + cv * (double)Wg[2 * (d + Dv)];
        a1 += nv * (double)Wg[2 * d + 1] + cv * (double)Wg[2 * (d + Dv) + 1];
    }
    #pragma unroll
    for (int off = 32; off; off >>= 1) { a0 += __shfl_xor(a0, off); a1 += __shfl_xor(a1, off); }
    if (lane == 0) {
        a0 += (double)bg[0]; a1 += (double)bg[1];
        double m = fmax(a0, a1);
        double e0 = exp(a0 - m), e1 = exp(a1 - m);
        double inv = 1.0 / (e0 + e1);
        gate[2 * t] = e0 * inv; gate[2 * t + 1] = e1 * inv;
    }
}

// ------- f64 top-k (sum of 2 score partials) + residual + tcoords + idx + fused LN2 (bf16 out) -------
__launch_bounds__(256)
__global__ void topk64_k(const double* __restrict__ s0, const float* __restrict__ x,
                         const float* __restrict__ emb, const float* __restrict__ coords,
                         const float* __restrict__ g2, const float* __restrict__ b2,
                         float* __restrict__ x2, __hip_bfloat16* __restrict__ normed2bf,
                         float* __restrict__ tcoords, float* __restrict__ idx_out)
{
    __shared__ double sc[4][Nv];
    const int wv = threadIdx.x >> 6, lane = threadIdx.x & 63;
    const int t = blockIdx.x * 4 + wv;
    const double* s1 = s0 + (size_t)NTOK * Nv;
    double* s = sc[wv];
    #pragma unroll
    for (int i = 0; i < 8; i++) {
        const size_t idx = (size_t)t * Nv + i * 64 + lane;
        s[i * 64 + lane] = s0[idx] + s1[idx];
    }
    __syncthreads();
    double wval[Kv]; int widx[Kv];
    for (int kk = 0; kk < Kv; kk++) {
        double bvv = -1e300; int bi = Nv;
        #pragma unroll
        for (int i = 0; i < 8; i++) {
            const int d = lane * 8 + i;
            const double vv = s[d];
            if (vv > bvv) { bvv = vv; bi = d; }
        }
        #pragma unroll
        for (int off = 1; off < 64; off <<= 1) {
            double ov = __shfl_xor(bvv, off);
            int    oi = __shfl_xor(bi, off);
            if (ov > bvv || (ov == bvv && oi < bi)) { bvv = ov; bi = oi; }
        }
        wval[kk] = bvv; widx[kk] = bi;
        __syncthreads();
        if (lane == (bi >> 3)) s[bi] = -1e301;
        __syncthreads();
        if (lane == kk) idx_out[(size_t)t * Kv + kk] = (float)bi;
    }
    double w[Kv]; double sum = 0.0;
    #pragma unroll
    for (int kk = 0; kk < Kv; kk++) { w[kk] = exp(wval[kk] - wval[0]); sum += w[kk]; }
    const double invs = 1.0 / sum;
    #pragma unroll
    for (int kk = 0; kk < Kv; kk++) w[kk] *= invs;
    float xv[8];
    float sm = 0.0f, sq = 0.0f;
    #pragma unroll
    for (int i = 0; i < 8; i++) {
        const int d = lane + 64 * i;
        double info = 0.0;
        #pragma unroll
        for (int kk = 0; kk < Kv; kk++)
            info = fma(w[kk], (double)emb[(size_t)widx[kk] * Dv + d], info);
        float vv = (float)((double)x[(size_t)t * Dv + d] + info);
        xv[i] = vv;
        x2[(size_t)t * Dv + d] = vv;
        sm += vv; sq += vv * vv;
    }
    #pragma unroll
    for (int off = 32; off; off >>= 1) { sm += __shfl_xor(sm, off); sq += __shfl_xor(sq, off); }
    const float mu = sm * (1.0f / Dv);
    const float var = sq * (1.0f / Dv) - mu * mu;
    const float rstd = rsqrtf(var + 1e-5f);
    #pragma unroll
    for (int i = 0; i < 8; i++) {
        const int d = lane + 64 * i;
        normed2bf[(size_t)t * Dv + d] = __float2bfloat16((xv[i] - mu) * rstd * g2[d] + b2[d]);
    }
    if (lane < NBv) {
        double tc = 0.0;
        #pragma unroll
        for (int kk = 0; kk < Kv; kk++)
            tc = fma(w[kk], (double)coords[(size_t)widx[kk] * NBv + lane], tc);
        tcoords[t * NBv + lane] = (float)tc;
    }
}

// ---------------- basis_A -> AcatT bf16 [nc][d] ----------------
__launch_bounds__(256)
__global__ void acatbf_k(const float* __restrict__ bA, __hip_bfloat16* __restrict__ AcatT)
{
    const int i = blockIdx.x * 256 + threadIdx.x;   // < 262144
    const int d = i & 511, nc = i >> 9;
    const int n = nc >> 6, r = nc & 63;
    AcatT[i] = __float2bfloat16(bA[n * 32768 + d * 64 + r]);
}

// ---------------- tiled transpose + f32->bf16: in [R][C] -> out [C][R] ----------------
__launch_bounds__(256)
__global__ void tr2bf_k(const float* __restrict__ in, __hip_bfloat16* __restrict__ out,
                        int R, int C)
{
    __shared__ float tile[32][33];
    const int c0 = blockIdx.x * 32, r0 = blockIdx.y * 32;
    const int tx = threadIdx.x & 31, ty = threadIdx.x >> 5;   // ty in 0..7
    #pragma unroll
    for (int i = 0; i < 4; i++)
        tile[ty + 8 * i][tx] = in[(size_t)(r0 + ty + 8 * i) * C + c0 + tx];
    __syncthreads();
    #pragma unroll
    for (int i = 0; i < 4; i++)
        out[(size_t)(c0 + ty + 8 * i) * R + r0 + tx] = __float2bfloat16(tile[tx][ty + 8 * i]);
}

// ---------------- combine: sum 4 G partials; h = sum_n c_n G_n ; u = c ⊗ h (bf16 out) ----------------
__launch_bounds__(256)
__global__ void combine_k(const float* __restrict__ Gp, const float* __restrict__ tcoords,
                          __hip_bfloat16* __restrict__ u_bf)
{
    const size_t M1 = (size_t)NTOK * Dv;
    const int wv = threadIdx.x >> 6, lane = threadIdx.x & 63;
    const int t = blockIdx.x * 4 + wv;
    float cs[NBv];
    #pragma unroll
    for (int n = 0; n < NBv; n++) cs[n] = tcoords[t * NBv + n];
    float h = 0.0f;
    #pragma unroll
    for (int n = 0; n < NBv; n++) {
        const size_t gi = (size_t)t * Dv + n * 64 + lane;
        float g = Gp[gi] + Gp[gi + M1] + Gp[gi + 2 * M1] + Gp[gi + 3 * M1];
        h = fmaf(cs[n], g, h);
    }
    #pragma unroll
    for (int n = 0; n < NBv; n++)
        u_bf[(size_t)t * Dv + n * 64 + lane] = __float2bfloat16(cs[n] * h);
}

// ---------------- reduce 4 split-K partials + bias + residual ----------------
__launch_bounds__(256)
__global__ void reduce4_k(const float* __restrict__ p4, const float* __restrict__ bd,
                          const float* __restrict__ x2, float* __restrict__ xout)
{
    const size_t M1 = (size_t)NTOK * Dv;
    const size_t i = (size_t)blockIdx.x * 256 + threadIdx.x;
    float c = p4[i] + p4[i + M1] + p4[i + 2 * M1] + p4[i + 3 * M1];
    xout[i] = c + bd[i & 511] + x2[i];
}

extern "C" void kernel_launch(void* const* d_in, const int* in_sizes, int n_in,
                              void* d_out, int out_size, void* d_ws, size_t ws_size,
                              hipStream_t stream) {
    (void)in_sizes; (void)n_in; (void)out_size; (void)ws_size;
    const size_t M1 = (size_t)NTOK * Dv;

    const float* x   = (const float*)d_in[0];
    const float* emb = (const float*)d_in[1];
    const float* Wq  = (const float*)d_in[2];
    const float* bq  = (const float*)d_in[3];
    const float* Wk  = (const float*)d_in[4];
    const float* bk  = (const float*)d_in[5];
    const float* Wv  = (const float*)d_in[6];
    const float* bvv = (const float*)d_in[7];
    const float* Wg  = (const float*)d_in[8];
    const float* bg  = (const float*)d_in[9];
    const float* bA  = (const float*)d_in[10];
    const float* bB  = (const float*)d_in[11];
    const float* crd = (const float*)d_in[12];
    const float* Wd  = (const float*)d_in[13];
    const float* bd  = (const float*)d_in[14];
    const float* l1g = (const float*)d_in[15];
    const float* l1b = (const float*)d_in[16];
    const float* l2g = (const float*)d_in[17];
    const float* l2b = (const float*)d_in[18];
    // d_in[19] = mask: causal tril, never read.

    double* normed64 = (double*)d_ws;                  // M1 d (8 MB)
    double* q64      = normed64 + M1;                  // M1 d
    double* k64      = q64 + M1;                       // M1 d
    double* v64      = k64 + M1;                       // M1 d
    double* ctx64    = v64 + M1;                       // M1 d
    double* Opart    = ctx64 + M1;                     // 1,572,864 d (12.58 MB)
    double* mbuf     = Opart + 1572864;                // 65536 d
    double* lbuf     = mbuf + 65536;                   // 65536 d
    double* gate64   = lbuf + 65536;                   // 4096 d
    float*  tcoords  = (float*)(gate64 + 4096);        // 16384 f
    __hip_bfloat16* AcatT = (__hip_bfloat16*)(tcoords + 16384);   // 262144 bf16

    // overlays
    double* s0 = q64;                                  // + s1 = k64 (contiguous)
    float*  x2 = (float*)v64;                          // M1 f (first 4 MB of v64)
    __hip_bfloat16* normed2bf = (__hip_bfloat16*)(x2 + M1);       // 2 MB
    __hip_bfloat16* u_bf      = normed2bf + M1;                   // 2 MB (v64 = 8 MB total)
    float* Gp = (float*)q64;                           // 4*M1 f over q64+k64
    float* p4 = (float*)q64;                           // reuse after Gp dead
    __hip_bfloat16* hf_bf = (__hip_bfloat16*)Opart;    // 4*M1 bf16 (8 MB)
    __hip_bfloat16* bBT   = hf_bf + 4 * M1;            // 2 MB
    __hip_bfloat16* WdT   = bBT + M1;                  // 2 MB   (total 12.5 <= 12.58 MB)

    float* xout    = (float*)d_out;
    float* idx_out = (float*)d_out + M1;

    ln64_k<<<NTOK, 256, 0, stream>>>(x, l1g, l1b, normed64);
    qkvMC_k<<<dim3(8, 64), 256, 0, stream>>>(normed64, Wq, Wk, Wv, bq, bk, bvv, q64, k64, v64);
    attn64c_k<<<dim3(32, 16, 4), 256, 0, stream>>>(q64, k64, v64, ctx64, Opart, mbuf, lbuf);
    attnmerge_k<<<(int)(M1 / 512), 256, 0, stream>>>(ctx64, Opart, mbuf, lbuf);
    gate64_k<<<NTOK / 4, 256, 0, stream>>>(normed64, ctx64, Wg, bg, gate64);
    scores64_k<<<dim3(8, 32, 2), 256, 0, stream>>>(normed64, ctx64, gate64, emb, s0);
    topk64_k<<<NTOK / 4, 256, 0, stream>>>(s0, x, emb, crd, l2g, l2b, x2, normed2bf, tcoords, idx_out);
    // weight preps (Opart dead after merge; s0 dead after topk)
    acatbf_k<<<1024, 256, 0, stream>>>(bA, AcatT);
    tr2bf_k<<<dim3(DFv / 32, Dv / 32), 256, 0, stream>>>(bB, bBT, Dv, DFv);   // bB [512][2048] -> [2048][512]
    tr2bf_k<<<dim3(Dv / 32, DFv / 32), 256, 0, stream>>>(Wd, WdT, DFv, Dv);   // Wd [2048][512] -> [512][2048]
    // G partials: normed2 @ Acat [2048x512x512] bf16 MFMA, split-K x4
    mfma_k<0><<<dim3(4, 16, 4), 256, 0, stream>>>(normed2bf, AcatT, Gp, NTOK, Dv, Dv, Dv / 4);
    combine_k<<<NTOK / 4, 256, 0, stream>>>(Gp, tcoords, u_bf);
    // hf = gelu(u @ bB) [2048x2048x512] bf16 MFMA
    mfma_k<1><<<dim3(16, 16, 1), 256, 0, stream>>>(u_bf, bBT, hf_bf, NTOK, DFv, Dv, Dv);
    // out partials: hf @ Wd [2048x512x2048] bf16 MFMA, split-K x4
    mfma_k<0><<<dim3(4, 16, 4), 256, 0, stream>>>(hf_bf, WdT, p4, NTOK, Dv, DFv, DFv / 4);
    reduce4_k<<<(int)(M1 / 256), 256, 0, stream>>>(p4, bd, x2, xout);
}

// Round 9
// 539.854 us; speedup vs baseline: 1.2575x; 1.1297x over previous
//
#include <hip/hip_runtime.h>
#include <hip/hip_bf16.h>

#define Bv 2
#define Sv 1024
#define Dv 512
#define Hv 8
#define Nv 512
#define Kv 16
#define NBv 8
#define DFv 2048
#define NTOK (Bv*Sv)   // 2048

typedef __attribute__((ext_vector_type(8))) short short8;
typedef __attribute__((ext_vector_type(4))) float float4v;
typedef __attribute__((ext_vector_type(4))) double dbl4;

// ---- fast f64 exp: range-reduced Taylor-13, ~1ulp, exp(x<=-708) -> 0 (proven r6/r8) ----
__device__ __forceinline__ double fexp64(double x)
{
    if (x < -708.0) return 0.0;
    const double SHIFT = 6755399441055744.0;            // 1.5 * 2^52
    double t  = fma(x, 1.4426950408889634074, SHIFT);
    double nd = t - SHIFT;                              // round(x * log2(e))
    double r  = fma(-nd, 6.93147180369123816490e-01, x);
    r         = fma(-nd, 1.90821492927058770002e-10, r);
    double p = 1.0 / 6227020800.0;                      // 1/13!
    p = fma(p, r, 1.0 / 479001600.0);
    p = fma(p, r, 1.0 / 39916800.0);
    p = fma(p, r, 1.0 / 3628800.0);
    p = fma(p, r, 1.0 / 362880.0);
    p = fma(p, r, 1.0 / 40320.0);
    p = fma(p, r, 1.0 / 5040.0);
    p = fma(p, r, 1.0 / 720.0);
    p = fma(p, r, 1.0 / 120.0);
    p = fma(p, r, 1.0 / 24.0);
    p = fma(p, r, 1.0 / 6.0);
    p = fma(p, r, 0.5);
    p = fma(p, r, 1.0);
    p = fma(p, r, 1.0);
    long long ni = (long long)nd;
    double s = __longlong_as_double((unsigned long long)(ni + 1023) << 52);
    return p * s;
}

// ---------------- LayerNorm f64 (f32 in / f64 out) ----------------
__launch_bounds__(256)
__global__ void ln64_k(const float* __restrict__ x, const float* __restrict__ g,
                       const float* __restrict__ b, double* __restrict__ out)
{
    const int t = blockIdx.x;
    const size_t base = (size_t)t * Dv;
    const int tid = threadIdx.x;
    double v0 = (double)x[base + tid];
    double v1 = (double)x[base + tid + 256];
    double s = v0 + v1, ss = v0 * v0 + v1 * v1;
    #pragma unroll
    for (int off = 32; off; off >>= 1) { s += __shfl_xor(s, off); ss += __shfl_xor(ss, off); }
    __shared__ double red[4][2];
    const int wv = tid >> 6, ln = tid & 63;
    if (ln == 0) { red[wv][0] = s; red[wv][1] = ss; }
    __syncthreads();
    s  = red[0][0] + red[1][0] + red[2][0] + red[3][0];
    ss = red[0][1] + red[1][1] + red[2][1] + red[3][1];
    double mu  = s * (1.0 / Dv);
    double var = ss * (1.0 / Dv) - mu * mu;
    double rstd = 1.0 / sqrt(var + 1e-5);
    out[base + tid]       = (v0 - mu) * rstd * (double)g[tid]       + (double)b[tid];
    out[base + tid + 256] = (v1 - mu) * rstd * (double)g[tid + 256] + (double)b[tid + 256];
}

// ---------------- fused QKV f64 GEMM, self-calibrating MFMA with scalar fallback ----------------
__launch_bounds__(256)
__global__ void qkvMC_k(const double* __restrict__ A,
                        const float* __restrict__ Wq, const float* __restrict__ Wk,
                        const float* __restrict__ Wv, const float* __restrict__ bq,
                        const float* __restrict__ bk, const float* __restrict__ bvv,
                        double* __restrict__ qo, double* __restrict__ ko,
                        double* __restrict__ vo)
{
    __shared__ double As[32][18];
    __shared__ double Bs[3][16][66];
    const int tid = threadIdx.x;
    const int n0 = blockIdx.x * 64, m0 = blockIdx.y * 32;
    const int w = tid >> 6, l = tid & 63;
    const int mt = (w >> 1) * 16, wc = (w & 1) * 32;
    const int ar = tid >> 3, ak = (tid & 7) * 2;
    const int bkk = tid >> 4, bn = (tid & 15) * 4;

    // ---- runtime layout probe (exact small-int arithmetic) ----
    int rA = 0, kA = 0, kB = 0, cB = 0, dsel = -1;
    #pragma unroll 1
    for (int ab = 0; ab < 4; ab++) {
        if (dsel >= 0) break;
        const int a_ = ab & 1, b_ = ab >> 1;
        const int rA_ = a_ ? (l >> 2) : (l & 15);
        const int kA_ = a_ ? (l & 3)  : (l >> 4);
        const int kB_ = b_ ? (l & 3)  : (l >> 4);
        const int cB_ = b_ ? (l >> 2) : (l & 15);
        const double av  = (double)(((rA_ * 37 + kA_ * 11) % 19) + 1);
        const double bvp = (double)(((kB_ * 23 + cB_ * 7) % 17) + 1);
        dbl4 dd = __builtin_amdgcn_mfma_f64_16x16x4f64(av, bvp, (dbl4){0.0, 0.0, 0.0, 0.0}, 0, 0, 0);
        #pragma unroll 1
        for (int d = 0; d < 4; d++) {
            if (dsel >= 0) break;
            int okv = 1;
            #pragma unroll
            for (int r = 0; r < 4; r++) {
                const int i_ = (d == 0) ? 4 * (l >> 4) + r
                             : (d == 1) ? (l & 15)
                             : (d == 2) ? (l >> 4) + 4 * r
                             :            (l & 15);
                const int j_ = (d == 0) ? (l & 15)
                             : (d == 1) ? 4 * (l >> 4) + r
                             : (d == 2) ? (l & 15)
                             :            (l >> 4) + 4 * r;
                double e = 0.0;
                #pragma unroll
                for (int kk2 = 0; kk2 < 4; kk2++)
                    e += (double)(((i_ * 37 + kk2 * 11) % 19) + 1)
                       * (double)(((kk2 * 23 + j_ * 7) % 17) + 1);
                okv &= (dd[r] == e) ? 1 : 0;
            }
            if (__all(okv)) { dsel = d; rA = rA_; kA = kA_; kB = kB_; cB = cB_; }
        }
    }

    auto stage = [&](int k0) {
        double2 avv = *(const double2*)(A + (size_t)(m0 + ar) * Dv + k0 + ak);
        *(double2*)&As[ar][ak] = avv;
        {
            float4 b4 = *(const float4*)(Wq + (size_t)(k0 + bkk) * Dv + n0 + bn);
            Bs[0][bkk][bn] = (double)b4.x; Bs[0][bkk][bn + 1] = (double)b4.y;
            Bs[0][bkk][bn + 2] = (double)b4.z; Bs[0][bkk][bn + 3] = (double)b4.w;
        }
        {
            float4 b4 = *(const float4*)(Wk + (size_t)(k0 + bkk) * Dv + n0 + bn);
            Bs[1][bkk][bn] = (double)b4.x; Bs[1][bkk][bn + 1] = (double)b4.y;
            Bs[1][bkk][bn + 2] = (double)b4.z; Bs[1][bkk][bn + 3] = (double)b4.w;
        }
        {
            float4 b4 = *(const float4*)(Wv + (size_t)(k0 + bkk) * Dv + n0 + bn);
            Bs[2][bkk][bn] = (double)b4.x; Bs[2][bkk][bn + 1] = (double)b4.y;
            Bs[2][bkk][bn + 2] = (double)b4.z; Bs[2][bkk][bn + 3] = (double)b4.w;
        }
    };

    if (dsel >= 0) {
        dbl4 acc[3][2];
        #pragma unroll
        for (int z = 0; z < 3; z++)
            #pragma unroll
            for (int nt = 0; nt < 2; nt++)
                acc[z][nt] = (dbl4){0.0, 0.0, 0.0, 0.0};
        for (int k0 = 0; k0 < Dv; k0 += 16) {
            __syncthreads();
            stage(k0);
            __syncthreads();
            #pragma unroll
            for (int s = 0; s < 4; s++) {
                const double aA = As[mt + rA][4 * s + kA];
                #pragma unroll
                for (int z = 0; z < 3; z++) {
                    const double b0 = Bs[z][4 * s + kB][wc + cB];
                    const double b1 = Bs[z][4 * s + kB][wc + 16 + cB];
                    acc[z][0] = __builtin_amdgcn_mfma_f64_16x16x4f64(aA, b0, acc[z][0], 0, 0, 0);
                    acc[z][1] = __builtin_amdgcn_mfma_f64_16x16x4f64(aA, b1, acc[z][1], 0, 0, 0);
                }
            }
        }
        #pragma unroll
        for (int r = 0; r < 4; r++) {
            const int i_ = (dsel == 0) ? 4 * (l >> 4) + r
                         : (dsel == 1) ? (l & 15)
                         : (dsel == 2) ? (l >> 4) + 4 * r
                         :               (l & 15);
            const int j_ = (dsel == 0) ? (l & 15)
                         : (dsel == 1) ? 4 * (l >> 4) + r
                         : (dsel == 2) ? (l & 15)
                         :               (l >> 4) + 4 * r;
            const int rowg = m0 + mt + i_;
            #pragma unroll
            for (int nt = 0; nt < 2; nt++) {
                const int colg = n0 + wc + nt * 16 + j_;
                qo[(size_t)rowg * Dv + colg] = acc[0][nt][r] + (double)bq[colg];
                ko[(size_t)rowg * Dv + colg] = acc[1][nt][r] + (double)bk[colg];
                vo[(size_t)rowg * Dv + colg] = acc[2][nt][r] + (double)bvv[colg];
            }
        }
    } else {
        double fac[3][8];
        #pragma unroll
        for (int z = 0; z < 3; z++)
            #pragma unroll
            for (int c = 0; c < 8; c++) fac[z][c] = 0.0;
        const int frow = mt + (l & 15);
        const int fcb  = wc + (l >> 4) * 8;
        for (int k0 = 0; k0 < Dv; k0 += 16) {
            __syncthreads();
            stage(k0);
            __syncthreads();
            #pragma unroll
            for (int kk = 0; kk < 16; kk++) {
                const double a = As[frow][kk];
                #pragma unroll
                for (int z = 0; z < 3; z++)
                    #pragma unroll
                    for (int c = 0; c < 8; c++)
                        fac[z][c] = fma(a, Bs[z][kk][fcb + c], fac[z][c]);
            }
        }
        const int rowg = m0 + frow;
        #pragma unroll
        for (int c = 0; c < 8; c++) {
            const int colg = n0 + fcb + c;
            qo[(size_t)rowg * Dv + colg] = fac[0][c] + (double)bq[colg];
            ko[(size_t)rowg * Dv + colg] = fac[1][c] + (double)bk[colg];
            vo[(size_t)rowg * Dv + colg] = fac[2][c] + (double)bvv[colg];
        }
    }
}

// ---------------- scores f64 GEMM, fused gating, split-K x2 (verified) ----------------
__launch_bounds__(256)
__global__ void scores64_k(const double* __restrict__ A0, const double* __restrict__ A1,
                           const double* __restrict__ gate, const float* __restrict__ Bm,
                           double* __restrict__ Cbase)
{
    const int M = NTOK, N = Nv, Kd = Dv;
    const int z = blockIdx.z;
    const int kbeg = z * (Dv / 2), kend = kbeg + Dv / 2;
    double* Cout = Cbase + (size_t)z * M * N;
    __shared__ double As[16][68];
    __shared__ double Bs[16][68];
    const int tid = threadIdx.x;
    const int m0 = blockIdx.y * 64, n0 = blockIdx.x * 64;
    const int tx = tid & 15, ty = tid >> 4;
    double acc[4][4] = {};
    const int lm = tid >> 2, lk4 = (tid & 3) << 2;
    for (int k0 = kbeg; k0 < kend; k0 += 16) {
        const double g0 = gate[2 * (m0 + lm)], g1 = gate[2 * (m0 + lm) + 1];
        double4 a0 = *(const double4*)(A0 + (size_t)(m0 + lm) * Kd + k0 + lk4);
        double4 a1 = *(const double4*)(A1 + (size_t)(m0 + lm) * Kd + k0 + lk4);
        As[lk4 + 0][lm] = g0 * a0.x + g1 * a1.x;
        As[lk4 + 1][lm] = g0 * a0.y + g1 * a1.y;
        As[lk4 + 2][lm] = g0 * a0.z + g1 * a1.z;
        As[lk4 + 3][lm] = g0 * a0.w + g1 * a1.w;
        const int nn = tid >> 2, kq = (tid & 3) << 2;
        float4 bv4 = *(const float4*)(Bm + (size_t)(n0 + nn) * Kd + k0 + kq);
        Bs[kq + 0][nn] = (double)bv4.x; Bs[kq + 1][nn] = (double)bv4.y;
        Bs[kq + 2][nn] = (double)bv4.z; Bs[kq + 3][nn] = (double)bv4.w;
        __syncthreads();
        #pragma unroll
        for (int kk = 0; kk < 16; kk++) {
            double a_[4], b_[4];
            *(double4*)a_ = *(const double4*)&As[kk][ty << 2];
            *(double4*)b_ = *(const double4*)&Bs[kk][tx << 2];
            #pragma unroll
            for (int i = 0; i < 4; i++)
                #pragma unroll
                for (int j = 0; j < 4; j++)
                    acc[i][j] = fma(a_[i], b_[j], acc[i][j]);
        }
        __syncthreads();
    }
    #pragma unroll
    for (int i = 0; i < 4; i++) {
        const int row = m0 + (ty << 2) + i;
        #pragma unroll
        for (int j = 0; j < 4; j++)
            Cout[(size_t)row * N + n0 + (tx << 2) + j] = acc[i][j];
    }
}

// ---------------- bf16 MFMA GEMM, 128x128 tile, BK=32, split-K via z ----------------
template<int EPI>
__launch_bounds__(256)
__global__ void mfma_k(const __hip_bfloat16* __restrict__ A, const __hip_bfloat16* __restrict__ B,
                       void* __restrict__ Cout_, int M, int N, int Kt, int kper)
{
    __shared__ __hip_bfloat16 As[128][40];
    __shared__ __hip_bfloat16 Bs[128][40];
    const int tid = threadIdx.x;
    const int m0 = blockIdx.y * 128, n0 = blockIdx.x * 128;
    const int z = blockIdx.z;
    const int kbeg = z * kper, kend = kbeg + kper;
    const int w = tid >> 6, l = tid & 63;
    const int wr = (w >> 1) * 64, wc = (w & 1) * 64;
    const int lm = l & 15, quad = l >> 4;
    float4v acc[4][4];
    #pragma unroll
    for (int i = 0; i < 4; i++)
        #pragma unroll
        for (int j = 0; j < 4; j++)
            acc[i][j] = (float4v){0.f, 0.f, 0.f, 0.f};
    const int srow = tid >> 1, skb = (tid & 1) * 16;
    for (int k0 = kbeg; k0 < kend; k0 += 32) {
        *(uint4*)&As[srow][skb]     = *(const uint4*)(A + (size_t)(m0 + srow) * Kt + k0 + skb);
        *(uint4*)&As[srow][skb + 8] = *(const uint4*)(A + (size_t)(m0 + srow) * Kt + k0 + skb + 8);
        *(uint4*)&Bs[srow][skb]     = *(const uint4*)(B + (size_t)(n0 + srow) * Kt + k0 + skb);
        *(uint4*)&Bs[srow][skb + 8] = *(const uint4*)(B + (size_t)(n0 + srow) * Kt + k0 + skb + 8);
        __syncthreads();
        short8 af[4], bf[4];
        #pragma unroll
        for (int mi = 0; mi < 4; mi++) af[mi] = *(const short8*)&As[wr + mi * 16 + lm][quad * 8];
        #pragma unroll
        for (int ni = 0; ni < 4; ni++) bf[ni] = *(const short8*)&Bs[wc + ni * 16 + lm][quad * 8];
        #pragma unroll
        for (int mi = 0; mi < 4; mi++)
            #pragma unroll
            for (int ni = 0; ni < 4; ni++)
                acc[mi][ni] = __builtin_amdgcn_mfma_f32_16x16x32_bf16(af[mi], bf[ni], acc[mi][ni], 0, 0, 0);
        __syncthreads();
    }
    #pragma unroll
    for (int mi = 0; mi < 4; mi++) {
        #pragma unroll
        for (int ni = 0; ni < 4; ni++) {
            const int col = n0 + wc + ni * 16 + lm;
            #pragma unroll
            for (int r = 0; r < 4; r++) {
                const int row = m0 + wr + mi * 16 + quad * 4 + r;
                float c = acc[mi][ni][r];
                if (EPI == 0) {
                    ((float*)Cout_)[(size_t)z * M * N + (size_t)row * N + col] = c;
                } else {
                    c = 0.5f * c * (1.0f + erff(c * 0.70710678118654752f));
                    ((__hip_bfloat16*)Cout_)[(size_t)row * N + col] = __float2bfloat16(c);
                }
            }
        }
    }
}

// ---------------- f64 flash attention: 64 q-rows/block, 4 KV chunks of 8 tiles ----------------
// Lane handles q-rows r and r+32 (qt pair 2qb, 2qb+1) with independent softmax states.
// Kt/Vs layouts and FP order identical to the r5/r8-verified 32-row kernel; K/V staging,
// barriers, and K/V LDS reads amortize over 2x the q rows. Merge kernel unchanged.
__device__ __constant__ int c_slotbase[4] = {0, 0, 384, 640};
__device__ __constant__ int c_cnt[4]      = {0, 24, 16, 8};

__launch_bounds__(256)
__global__ void attn64w_k(const double* __restrict__ q, const double* __restrict__ k,
                          const double* __restrict__ v, double* __restrict__ ctxun,
                          double* __restrict__ Opart, double* __restrict__ mbuf,
                          double* __restrict__ lbuf)
{
    const int qb = blockIdx.x, bh = blockIdx.y, ch = blockIdx.z;
    if (qb < ch * 4) return;
    const int b = bh >> 3, h = bh & 7;
    __shared__ double Qs[64][70];
    __shared__ double Kt[64][34];
    __shared__ double Vs[32][70];
    const int tid = threadIdx.x;
    const int r = tid >> 3, cc = tid & 7;
    const int lane = tid & 63;
    const int lbase = lane & 56;
    const size_t qoff = ((size_t)(b * Sv + qb * 64)) * Dv + h * 64;
    #pragma unroll
    for (int i = 0; i < 8; i++) {
        int f = i * 256 + tid;
        int row = f >> 5, c2 = (f & 31) * 2;
        *(double2*)&Qs[row][c2] = *(const double2*)(q + qoff + (size_t)row * Dv + c2);
    }
    double O0[8] = {}, O1[8] = {};
    double m0 = -1e300, l0 = 0.0;
    double m1 = -1e300, l1 = 0.0;
    const int ig0 = qb * 64 + r;
    const int ig1 = qb * 64 + 32 + r;
    const int jbeg = ch * 8;
    const int jend = (ch * 8 + 7 < 2 * qb + 1) ? ch * 8 + 7 : 2 * qb + 1;
    for (int jt = jbeg; jt <= jend; jt++) {
        __syncthreads();
        const size_t koff = ((size_t)(b * Sv + jt * 32)) * Dv + h * 64;
        #pragma unroll
        for (int i = 0; i < 4; i++) {
            int f = i * 256 + tid;
            int row = f >> 5, c2 = (f & 31) * 2;
            double2 kv = *(const double2*)(k + koff + (size_t)row * Dv + c2);
            Kt[c2][row]     = kv.x;
            Kt[c2 + 1][row] = kv.y;
            *(double2*)&Vs[row][c2] = *(const double2*)(v + koff + (size_t)row * Dv + c2);
        }
        __syncthreads();
        double a0[4] = {0.0, 0.0, 0.0, 0.0};
        double a1[4] = {0.0, 0.0, 0.0, 0.0};
        #pragma unroll 8
        for (int kk = 0; kk < 64; kk += 2) {
            double2 qv0 = *(const double2*)&Qs[r][kk];
            double2 qv1 = *(const double2*)&Qs[32 + r][kk];
            double2 ka0 = *(const double2*)&Kt[kk][cc * 4];
            double2 ka1 = *(const double2*)&Kt[kk][cc * 4 + 2];
            double2 kb0 = *(const double2*)&Kt[kk + 1][cc * 4];
            double2 kb1 = *(const double2*)&Kt[kk + 1][cc * 4 + 2];
            a0[0] = fma(qv0.x, ka0.x, fma(qv0.y, kb0.x, a0[0]));
            a0[1] = fma(qv0.x, ka0.y, fma(qv0.y, kb0.y, a0[1]));
            a0[2] = fma(qv0.x, ka1.x, fma(qv0.y, kb1.x, a0[2]));
            a0[3] = fma(qv0.x, ka1.y, fma(qv0.y, kb1.y, a0[3]));
            a1[0] = fma(qv1.x, ka0.x, fma(qv1.y, kb0.x, a1[0]));
            a1[1] = fma(qv1.x, ka0.y, fma(qv1.y, kb0.y, a1[1]));
            a1[2] = fma(qv1.x, ka1.x, fma(qv1.y, kb1.x, a1[2]));
            a1[3] = fma(qv1.x, ka1.y, fma(qv1.y, kb1.y, a1[3]));
        }
        double p0[4], p1[4];
        double mx0 = -1e300, mx1 = -1e300;
        #pragma unroll
        for (int jj = 0; jj < 4; jj++) {
            const int jglob = jt * 32 + cc * 4 + jj;
            p0[jj] = (jglob <= ig0) ? a0[jj] * 0.125 : -1e300;
            p1[jj] = (jglob <= ig1) ? a1[jj] * 0.125 : -1e300;
            mx0 = fmax(mx0, p0[jj]);
            mx1 = fmax(mx1, p1[jj]);
        }
        mx0 = fmax(mx0, __shfl_xor(mx0, 1)); mx1 = fmax(mx1, __shfl_xor(mx1, 1));
        mx0 = fmax(mx0, __shfl_xor(mx0, 2)); mx1 = fmax(mx1, __shfl_xor(mx1, 2));
        mx0 = fmax(mx0, __shfl_xor(mx0, 4)); mx1 = fmax(mx1, __shfl_xor(mx1, 4));
        const double mn0 = fmax(m0, mx0), mn1 = fmax(m1, mx1);
        double rs0 = 0.0, rs1 = 0.0;
        #pragma unroll
        for (int jj = 0; jj < 4; jj++) {
            p0[jj] = fexp64(p0[jj] - mn0); rs0 += p0[jj];
            p1[jj] = fexp64(p1[jj] - mn1); rs1 += p1[jj];
        }
        rs0 += __shfl_xor(rs0, 1); rs1 += __shfl_xor(rs1, 1);
        rs0 += __shfl_xor(rs0, 2); rs1 += __shfl_xor(rs1, 2);
        rs0 += __shfl_xor(rs0, 4); rs1 += __shfl_xor(rs1, 4);
        const double al0 = fexp64(m0 - mn0), al1 = fexp64(m1 - mn1);
        l0 = l0 * al0 + rs0; m0 = mn0;
        l1 = l1 * al1 + rs1; m1 = mn1;
        #pragma unroll
        for (int c = 0; c < 8; c++) { O0[c] *= al0; O1[c] *= al1; }
        #pragma unroll
        for (int jsrc = 0; jsrc < 8; jsrc++) {
            #pragma unroll
            for (int jj = 0; jj < 4; jj++) {
                const double pj0 = __shfl(p0[jj], lbase + jsrc);
                const double pj1 = __shfl(p1[jj], lbase + jsrc);
                const double* vrow = &Vs[jsrc * 4 + jj][cc * 8];
                #pragma unroll
                for (int c2 = 0; c2 < 8; c2 += 2) {
                    double2 vv = *(const double2*)&vrow[c2];
                    O0[c2 + 0] = fma(pj0, vv.x, O0[c2 + 0]);
                    O0[c2 + 1] = fma(pj0, vv.y, O0[c2 + 1]);
                    O1[c2 + 0] = fma(pj1, vv.x, O1[c2 + 0]);
                    O1[c2 + 1] = fma(pj1, vv.y, O1[c2 + 1]);
                }
            }
        }
    }
    const int qt0 = 2 * qb, qt1 = 2 * qb + 1;
    if (cc == 0) {
        const int mi0 = ((bh * 32 + qt0) * 4 + ch) * 32 + r;
        mbuf[mi0] = m0; lbuf[mi0] = l0;
        const int mi1 = ((bh * 32 + qt1) * 4 + ch) * 32 + r;
        mbuf[mi1] = m1; lbuf[mi1] = l1;
    }
    if (ch == 0) {
        const size_t ob0 = ((size_t)(b * Sv + ig0)) * Dv + h * 64 + cc * 8;
        const size_t ob1 = ((size_t)(b * Sv + ig1)) * Dv + h * 64 + cc * 8;
        #pragma unroll
        for (int c2 = 0; c2 < 8; c2 += 2) {
            double2 t0{O0[c2], O0[c2 + 1]}; *(double2*)(ctxun + ob0 + c2) = t0;
            double2 t1{O1[c2], O1[c2 + 1]}; *(double2*)(ctxun + ob1 + c2) = t1;
        }
    } else {
        const int slot0 = c_slotbase[ch] + bh * c_cnt[ch] + (qt0 - ch * 8);
        const int slot1 = slot0 + 1;
        const size_t ob0 = ((size_t)slot0 * 32 + r) * 64 + cc * 8;
        const size_t ob1 = ((size_t)slot1 * 32 + r) * 64 + cc * 8;
        #pragma unroll
        for (int c2 = 0; c2 < 8; c2 += 2) {
            double2 t0{O0[c2], O0[c2 + 1]}; *(double2*)(Opart + ob0 + c2) = t0;
            double2 t1{O1[c2], O1[c2 + 1]}; *(double2*)(Opart + ob1 + c2) = t1;
        }
    }
}

// ---------------- merge up to 4 KV chunks (exact flash combine, unchanged) ----------------
__launch_bounds__(256)
__global__ void attnmerge_k(double* __restrict__ ctx, const double* __restrict__ Opart,
                            const double* __restrict__ mbuf, const double* __restrict__ lbuf)
{
    const size_t i = (size_t)blockIdx.x * 256 + threadIdx.x;   // double2 index
    const size_t e = i * 2;
    const int d = (int)(e & 511);
    const int s = (int)((e >> 9) & 1023);
    const int b = (int)(e >> 19);
    const int h = d >> 6;
    const int qt = s >> 5, r = s & 31;
    const int bh = b * 8 + h;
    int nch = qt >> 3; if (nch > 3) nch = 3;
    const int mib = ((bh * 32 + qt) * 4) * 32 + r;
    double ms = mbuf[mib];
    for (int c = 1; c <= nch; c++) ms = fmax(ms, mbuf[mib + c * 32]);
    double2 o = *(const double2*)(ctx + e);
    double a0 = exp(mbuf[mib] - ms);
    double den = lbuf[mib] * a0;
    o.x *= a0; o.y *= a0;
    for (int c = 1; c <= nch; c++) {
        const double ac = exp(mbuf[mib + c * 32] - ms);
        den += lbuf[mib + c * 32] * ac;
        const int slot = c_slotbase[c] + bh * c_cnt[c] + (qt - c * 8);
        const size_t op = ((size_t)slot * 32 + r) * 64 + (d & 63);
        double2 oc = *(const double2*)(Opart + op);
        o.x = fma(ac, oc.x, o.x);
        o.y = fma(ac, oc.y, o.y);
    }
    const double inv = 1.0 / den;
    o.x *= inv; o.y *= inv;
    *(double2*)(ctx + e) = o;
}

// ---------------- f64 gate ----------------
__launch_bounds__(256)
__global__ void gate64_k(const double* __restrict__ normed, const double* __restrict__ ctx,
                         const float* __restrict__ Wg, const float* __restrict__ bg,
                         double* __restrict__ gate)
{
    const int wv = threadIdx.x >> 6, lane = threadIdx.x & 63;
    const int t = blockIdx.x * 4 + wv;
    double a0 = 0.0, a1 = 0.0;
    for (int d = lane; d < Dv; d += 64) {
        double nv = normed[(size_t)t * Dv + d];
        double cv = ctx[(size_t)t * Dv + d];
        a0 += nv * (double)Wg[2 * d]     + cv * (double)Wg[2 * (d + Dv)];
        a1 += nv * (double)Wg[2 * d + 1] + cv * (double)Wg[2 * (d + Dv) + 1];
    }
    #pragma unroll
    for (int off = 32; off; off >>= 1) { a0 += __shfl_xor(a0, off); a1 += __shfl_xor(a1, off); }
    if (lane == 0) {
        a0 += (double)bg[0]; a1 += (double)bg[1];
        double m = fmax(a0, a1);
        double e0 = exp(a0 - m), e1 = exp(a1 - m);
        double inv = 1.0 / (e0 + e1);
        gate[2 * t] = e0 * inv; gate[2 * t + 1] = e1 * inv;
    }
}

// ------- f64 top-k (sum of 2 score partials) + residual + tcoords + idx + fused LN2 (bf16 out) -------
__launch_bounds__(256)
__global__ void topk64_k(const double* __restrict__ s0, const float* __restrict__ x,
                         const float* __restrict__ emb, const float* __restrict__ coords,
                         const float* __restrict__ g2, const float* __restrict__ b2,
                         float* __restrict__ x2, __hip_bfloat16* __restrict__ normed2bf,
                         float* __restrict__ tcoords, float* __restrict__ idx_out)
{
    __shared__ double sc[4][Nv];
    const int wv = threadIdx.x >> 6, lane = threadIdx.x & 63;
    const int t = blockIdx.x * 4 + wv;
    const double* s1 = s0 + (size_t)NTOK * Nv;
    double* s = sc[wv];
    #pragma unroll
    for (int i = 0; i < 8; i++) {
        const size_t idx = (size_t)t * Nv + i * 64 + lane;
        s[i * 64 + lane] = s0[idx] + s1[idx];
    }
    __syncthreads();
    double wval[Kv]; int widx[Kv];
    for (int kk = 0; kk < Kv; kk++) {
        double bvv = -1e300; int bi = Nv;
        #pragma unroll
        for (int i = 0; i < 8; i++) {
            const int d = lane * 8 + i;
            const double vv = s[d];
            if (vv > bvv) { bvv = vv; bi = d; }
        }
        #pragma unroll
        for (int off = 1; off < 64; off <<= 1) {
            double ov = __shfl_xor(bvv, off);
            int    oi = __shfl_xor(bi, off);
            if (ov > bvv || (ov == bvv && oi < bi)) { bvv = ov; bi = oi; }
        }
        wval[kk] = bvv; widx[kk] = bi;
        __syncthreads();
        if (lane == (bi >> 3)) s[bi] = -1e301;
        __syncthreads();
        if (lane == kk) idx_out[(size_t)t * Kv + kk] = (float)bi;
    }
    double w[Kv]; double sum = 0.0;
    #pragma unroll
    for (int kk = 0; kk < Kv; kk++) { w[kk] = exp(wval[kk] - wval[0]); sum += w[kk]; }
    const double invs = 1.0 / sum;
    #pragma unroll
    for (int kk = 0; kk < Kv; kk++) w[kk] *= invs;
    float xv[8];
    float sm = 0.0f, sq = 0.0f;
    #pragma unroll
    for (int i = 0; i < 8; i++) {
        const int d = lane + 64 * i;
        double info = 0.0;
        #pragma unroll
        for (int kk = 0; kk < Kv; kk++)
            info = fma(w[kk], (double)emb[(size_t)widx[kk] * Dv + d], info);
        float vv = (float)((double)x[(size_t)t * Dv + d] + info);
        xv[i] = vv;
        x2[(size_t)t * Dv + d] = vv;
        sm += vv; sq += vv * vv;
    }
    #pragma unroll
    for (int off = 32; off; off >>= 1) { sm += __shfl_xor(sm, off); sq += __shfl_xor(sq, off); }
    const float mu = sm * (1.0f / Dv);
    const float var = sq * (1.0f / Dv) - mu * mu;
    const float rstd = rsqrtf(var + 1e-5f);
    #pragma unroll
    for (int i = 0; i < 8; i++) {
        const int d = lane + 64 * i;
        normed2bf[(size_t)t * Dv + d] = __float2bfloat16((xv[i] - mu) * rstd * g2[d] + b2[d]);
    }
    if (lane < NBv) {
        double tc = 0.0;
        #pragma unroll
        for (int kk = 0; kk < Kv; kk++)
            tc = fma(w[kk], (double)coords[(size_t)widx[kk] * NBv + lane], tc);
        tcoords[t * NBv + lane] = (float)tc;
    }
}

// ---------------- basis_A -> AcatT bf16 [nc][d] ----------------
__launch_bounds__(256)
__global__ void acatbf_k(const float* __restrict__ bA, __hip_bfloat16* __restrict__ AcatT)
{
    const int i = blockIdx.x * 256 + threadIdx.x;   // < 262144
    const int d = i & 511, nc = i >> 9;
    const int n = nc >> 6, r = nc & 63;
    AcatT[i] = __float2bfloat16(bA[n * 32768 + d * 64 + r]);
}

// ---------------- tiled transpose + f32->bf16: in [R][C] -> out [C][R] ----------------
__launch_bounds__(256)
__global__ void tr2bf_k(const float* __restrict__ in, __hip_bfloat16* __restrict__ out,
                        int R, int C)
{
    __shared__ float tile[32][33];
    const int c0 = blockIdx.x * 32, r0 = blockIdx.y * 32;
    const int tx = threadIdx.x & 31, ty = threadIdx.x >> 5;   // ty in 0..7
    #pragma unroll
    for (int i = 0; i < 4; i++)
        tile[ty + 8 * i][tx] = in[(size_t)(r0 + ty + 8 * i) * C + c0 + tx];
    __syncthreads();
    #pragma unroll
    for (int i = 0; i < 4; i++)
        out[(size_t)(c0 + ty + 8 * i) * R + r0 + tx] = __float2bfloat16(tile[tx][ty + 8 * i]);
}

// ---------------- combine: sum 4 G partials; h = sum_n c_n G_n ; u = c ⊗ h (bf16 out) ----------------
__launch_bounds__(256)
__global__ void combine_k(const float* __restrict__ Gp, const float* __restrict__ tcoords,
                          __hip_bfloat16* __restrict__ u_bf)
{
    const size_t M1 = (size_t)NTOK * Dv;
    const int wv = threadIdx.x >> 6, lane = threadIdx.x & 63;
    const int t = blockIdx.x * 4 + wv;
    float cs[NBv];
    #pragma unroll
    for (int n = 0; n < NBv; n++) cs[n] = tcoords[t * NBv + n];
    float h = 0.0f;
    #pragma unroll
    for (int n = 0; n < NBv; n++) {
        const size_t gi = (size_t)t * Dv + n * 64 + lane;
        float g = Gp[gi] + Gp[gi + M1] + Gp[gi + 2 * M1] + Gp[gi + 3 * M1];
        h = fmaf(cs[n], g, h);
    }
    #pragma unroll
    for (int n = 0; n < NBv; n++)
        u_bf[(size_t)t * Dv + n * 64 + lane] = __float2bfloat16(cs[n] * h);
}

// ---------------- reduce 4 split-K partials + bias + residual ----------------
__launch_bounds__(256)
__global__ void reduce4_k(const float* __restrict__ p4, const float* __restrict__ bd,
                          const float* __restrict__ x2, float* __restrict__ xout)
{
    const size_t M1 = (size_t)NTOK * Dv;
    const size_t i = (size_t)blockIdx.x * 256 + threadIdx.x;
    float c = p4[i] + p4[i + M1] + p4[i + 2 * M1] + p4[i + 3 * M1];
    xout[i] = c + bd[i & 511] + x2[i];
}

extern "C" void kernel_launch(void* const* d_in, const int* in_sizes, int n_in,
                              void* d_out, int out_size, void* d_ws, size_t ws_size,
                              hipStream_t stream) {
    (void)in_sizes; (void)n_in; (void)out_size; (void)ws_size;
    const size_t M1 = (size_t)NTOK * Dv;

    const float* x   = (const float*)d_in[0];
    const float* emb = (const float*)d_in[1];
    const float* Wq  = (const float*)d_in[2];
    const float* bq  = (const float*)d_in[3];
    const float* Wk  = (const float*)d_in[4];
    const float* bk  = (const float*)d_in[5];
    const float* Wv  = (const float*)d_in[6];
    const float* bvv = (const float*)d_in[7];
    const float* Wg  = (const float*)d_in[8];
    const float* bg  = (const float*)d_in[9];
    const float* bA  = (const float*)d_in[10];
    const float* bB  = (const float*)d_in[11];
    const float* crd = (const float*)d_in[12];
    const float* Wd  = (const float*)d_in[13];
    const float* bd  = (const float*)d_in[14];
    const float* l1g = (const float*)d_in[15];
    const float* l1b = (const float*)d_in[16];
    const float* l2g = (const float*)d_in[17];
    const float* l2b = (const float*)d_in[18];
    // d_in[19] = mask: causal tril, never read.

    double* normed64 = (double*)d_ws;                  // M1 d (8 MB)
    double* q64      = normed64 + M1;                  // M1 d
    double* k64      = q64 + M1;                       // M1 d
    double* v64      = k64 + M1;                       // M1 d
    double* ctx64    = v64 + M1;                       // M1 d
    double* Opart    = ctx64 + M1;                     // 1,572,864 d (12.58 MB)
    double* mbuf     = Opart + 1572864;                // 65536 d
    double* lbuf     = mbuf + 65536;                   // 65536 d
    double* gate64   = lbuf + 65536;                   // 4096 d
    float*  tcoords  = (float*)(gate64 + 4096);        // 16384 f
    __hip_bfloat16* AcatT = (__hip_bfloat16*)(tcoords + 16384);   // 262144 bf16

    // overlays
    double* s0 = q64;                                  // + s1 = k64 (contiguous)
    float*  x2 = (float*)v64;                          // M1 f (first 4 MB of v64)
    __hip_bfloat16* normed2bf = (__hip_bfloat16*)(x2 + M1);       // 2 MB
    __hip_bfloat16* u_bf      = normed2bf + M1;                   // 2 MB (v64 = 8 MB total)
    float* Gp = (float*)q64;                           // 4*M1 f over q64+k64
    float* p4 = (float*)q64;                           // reuse after Gp dead
    __hip_bfloat16* hf_bf = (__hip_bfloat16*)Opart;    // 4*M1 bf16 (8 MB)
    __hip_bfloat16* bBT   = hf_bf + 4 * M1;            // 2 MB
    __hip_bfloat16* WdT   = bBT + M1;                  // 2 MB   (total 12.5 <= 12.58 MB)

    float* xout    = (float*)d_out;
    float* idx_out = (float*)d_out + M1;

    ln64_k<<<NTOK, 256, 0, stream>>>(x, l1g, l1b, normed64);
    qkvMC_k<<<dim3(8, 64), 256, 0, stream>>>(normed64, Wq, Wk, Wv, bq, bk, bvv, q64, k64, v64);
    attn64w_k<<<dim3(16, 16, 4), 256, 0, stream>>>(q64, k64, v64, ctx64, Opart, mbuf, lbuf);
    attnmerge_k<<<(int)(M1 / 512), 256, 0, stream>>>(ctx64, Opart, mbuf, lbuf);
    gate64_k<<<NTOK / 4, 256, 0, stream>>>(normed64, ctx64, Wg, bg, gate64);
    scores64_k<<<dim3(8, 32, 2), 256, 0, stream>>>(normed64, ctx64, gate64, emb, s0);
    topk64_k<<<NTOK / 4, 256, 0, stream>>>(s0, x, emb, crd, l2g, l2b, x2, normed2bf, tcoords, idx_out);
    // weight preps (Opart dead after merge; s0 dead after topk)
    acatbf_k<<<1024, 256, 0, stream>>>(bA, AcatT);
    tr2bf_k<<<dim3(DFv / 32, Dv / 32), 256, 0, stream>>>(bB, bBT, Dv, DFv);   // bB [512][2048] -> [2048][512]
    tr2bf_k<<<dim3(Dv / 32, DFv / 32), 256, 0, stream>>>(Wd, WdT, DFv, Dv);   // Wd [2048][512] -> [512][2048]
    // G partials: normed2 @ Acat [2048x512x512] bf16 MFMA, split-K x4
    mfma_k<0><<<dim3(4, 16, 4), 256, 0, stream>>>(normed2bf, AcatT, Gp, NTOK, Dv, Dv, Dv / 4);
    combine_k<<<NTOK / 4, 256, 0, stream>>>(Gp, tcoords, u_bf);
    // hf = gelu(u @ bB) [2048x2048x512] bf16 MFMA
    mfma_k<1><<<dim3(16, 16, 1), 256, 0, stream>>>(u_bf, bBT, hf_bf, NTOK, DFv, Dv, Dv);
    // out partials: hf @ Wd [2048x512x2048] bf16 MFMA, split-K x4
    mfma_k<0><<<dim3(4, 16, 4), 256, 0, stream>>>(hf_bf, WdT, p4, NTOK, Dv, DFv, DFv / 4);
    reduce4_k<<<(int)(M1 / 256), 256, 0, stream>>>(p4, bd, x2, xout);
}